// Round 1
// baseline (569.672 us; speedup 1.0000x reference)
//
#include <hip/hip_runtime.h>
#include <hip/hip_bf16.h>
#include <math.h>

#define N1C 50176
#define N2C 12544
#define N3C 3136

typedef __attribute__((ext_vector_type(8))) short bf16x8;
typedef __attribute__((ext_vector_type(4))) float f32x4;

__device__ __forceinline__ unsigned short f2bf(float f) {
    unsigned u = __builtin_bit_cast(unsigned, f);
    u += 0x7fffu + ((u >> 16) & 1u);
    return (unsigned short)(u >> 16);
}
__device__ __forceinline__ unsigned packbf(float a, float b) {
    return (unsigned)f2bf(a) | ((unsigned)f2bf(b) << 16);
}

// ---------------- transpose x (B,3,N1) -> X0 [n][c*8+b] ----------------
__global__ void transpose_x(const float* __restrict__ x, float* __restrict__ X0) {
    __shared__ float T[64][25];
    int n0 = blockIdx.x * 64;
    int tid = threadIdx.x;
    for (int r = tid; r < 24 * 64; r += 256) {
        int cb = r >> 6;          // b*3+c
        int nn = r & 63;
        T[nn][cb] = x[cb * N1C + n0 + nn];
    }
    __syncthreads();
    for (int w = tid; w < 64 * 24; w += 256) {
        int nn = w / 24;
        int cc = w - nn * 24;     // c*8+b
        int c = cc >> 3, b = cc & 7;
        X0[(n0 + nn) * 24 + cc] = T[nn][b * 3 + c];
    }
}

// ---------------- MLP: a[n][k][t] ----------------
__global__ void mlp_kernel(const float* __restrict__ off,
                           const float* __restrict__ Wh, const float* __restrict__ bh,
                           const float* __restrict__ Wo, const float* __restrict__ bo,
                           float* __restrict__ A, int total) {
    int idx = blockIdx.x * 256 + threadIdx.x;
    if (idx >= total) return;
    float o0 = off[idx * 2], o1 = off[idx * 2 + 1];
    float out[9];
#pragma unroll
    for (int t = 0; t < 9; t++) out[t] = bo[t];
#pragma unroll
    for (int h = 0; h < 32; h++) {
        float hv = fmaxf(o0 * Wh[h] + o1 * Wh[32 + h] + bh[h], 0.f);
#pragma unroll
        for (int t = 0; t < 9; t++) out[t] += hv * Wo[h * 9 + t];
    }
#pragma unroll
    for (int t = 0; t < 9; t++) A[idx * 9 + t] = out[t];
}

// ---------------- fused interp-conv ----------------
// Xin: [Nin][CIN*8]  (bn(scale,shift)+relu applied on gather if bnsc != null)
// Y:   [N2][OC_total][8]  (pre-BN)
// bnsum/bnsq: per-o sum / sumsq partials (double)
template <int CIN>
__global__ __launch_bounds__(256, 2)
void conv_kernel(const float* __restrict__ Xin,
                 const int* __restrict__ nbr,
                 const float* __restrict__ A,
                 const float* __restrict__ W,      // [OC_total][CIN][9]
                 const float* __restrict__ bias,   // [OC_total]
                 const float* __restrict__ bnsc,
                 const float* __restrict__ bnsh,
                 float* __restrict__ Y,
                 double* __restrict__ bnsum,
                 double* __restrict__ bnsq,
                 int OC_total) {
    constexpr int KROW = (CIN == 3) ? 32 : 320;   // padded K: 10 slots per c, mult of 32
    constexpr int KSTR = KROW + 8;                // +16B pad vs bank aliasing
    constexpr int KT = KROW / 32;
    constexpr int CB = CIN * 8;

    __shared__ short Wl[32 * KSTR];
    __shared__ short S[64 * KSTR];
    __shared__ double redd[4][64];

    int tid = threadIdx.x;
    int obase = blockIdx.y * 32;
    int tile = blockIdx.x;                        // 8 nodes per block

    // stage W (bf16, zero-padded slots)
    for (int i = tid; i < 32 * KROW; i += 256) {
        int o = i / KROW, kk = i - o * KROW;
        int c = kk / 10, t = kk - c * 10;
        float v = (t < 9 && c < CIN) ? W[((obase + o) * CIN + c) * 9 + t] : 0.f;
        Wl[o * KSTR + kk] = (short)f2bf(v);
    }
    // zero S once (pad slots stay zero; data slots get overwritten)
    for (int i = tid; i < 64 * KSTR; i += 256) S[i] = 0;
    __syncthreads();

    // ---- s phase: s[col][c*10+t] = sum_k a[n,k,t] * feat(c,b,k) ----
    if constexpr (CIN == 3) {
        if (tid < 192) {
            int nsub = tid / 24;
            int cb = tid - nsub * 24;
            int c = cb >> 3, b = cb & 7;
            int n = tile * 8 + nsub;
            float s[9];
#pragma unroll
            for (int t = 0; t < 9; t++) s[t] = 0.f;
#pragma unroll
            for (int k = 0; k < 9; k++) {
                int j = nbr[n * 9 + k];
                float f = Xin[j * CB + cb];
#pragma unroll
                for (int t = 0; t < 9; t++) s[t] += A[n * 81 + k * 9 + t] * f;
            }
            int col = nsub * 8 + b;
            unsigned* dp = (unsigned*)&S[col * KSTR + c * 10];
            dp[0] = packbf(s[0], s[1]);
            dp[1] = packbf(s[2], s[3]);
            dp[2] = packbf(s[4], s[5]);
            dp[3] = packbf(s[6], s[7]);
            dp[4] = packbf(s[8], 0.f);
        }
    } else {
        int c = tid >> 3, b = tid & 7;
        float sc = 1.f, sh = 0.f;
        if (bnsc) { sc = bnsc[c]; sh = bnsh[c]; }
        for (int nsub = 0; nsub < 8; nsub++) {
            int n = tile * 8 + nsub;                 // block-uniform -> s_loads below
            const float* Ar = A + n * 81;
            float s[9];
#pragma unroll
            for (int t = 0; t < 9; t++) s[t] = 0.f;
#pragma unroll
            for (int k = 0; k < 9; k++) {
                int j = nbr[n * 9 + k];              // uniform
                float f = Xin[j * CB + tid];         // coalesced 1KB per k
                f = fmaxf(f * sc + sh, 0.f);
#pragma unroll
                for (int t = 0; t < 9; t++) s[t] += Ar[k * 9 + t] * f;
            }
            int col = nsub * 8 + b;
            unsigned* dp = (unsigned*)&S[col * KSTR + c * 10];
            dp[0] = packbf(s[0], s[1]);
            dp[1] = packbf(s[2], s[3]);
            dp[2] = packbf(s[4], s[5]);
            dp[3] = packbf(s[6], s[7]);
            dp[4] = packbf(s[8], 0.f);
        }
    }
    __syncthreads();

    // ---- MFMA: Y[o][col] = Wl[o][k'] * S[col][k'] ----
    int lane = tid & 63;
    int wv = tid >> 6;          // N-tile per wave
    int q = lane >> 4;
    int cl = lane & 15;
    int colg = wv * 16 + cl;

    f32x4 acc0 = {0.f, 0.f, 0.f, 0.f};
    f32x4 acc1 = {0.f, 0.f, 0.f, 0.f};
#pragma unroll
    for (int kt = 0; kt < KT; kt++) {
        bf16x8 bf = *(bf16x8*)&S[colg * KSTR + kt * 32 + q * 8];
        bf16x8 a0 = *(bf16x8*)&Wl[cl * KSTR + kt * 32 + q * 8];
        bf16x8 a1 = *(bf16x8*)&Wl[(cl + 16) * KSTR + kt * 32 + q * 8];
        acc0 = __builtin_amdgcn_mfma_f32_16x16x32_bf16(a0, bf, acc0, 0, 0, 0);
        acc1 = __builtin_amdgcn_mfma_f32_16x16x32_bf16(a1, bf, acc1, 0, 0, 0);
    }

    // ---- epilogue: bias, store, BN partials (double) ----
    int node = tile * 8 + (colg >> 3);
    int b = colg & 7;
    double psum[8], psq[8];
#pragma unroll
    for (int m = 0; m < 2; m++) {
        f32x4 ac = m ? acc1 : acc0;
#pragma unroll
        for (int i = 0; i < 4; i++) {
            int o = obase + m * 16 + q * 4 + i;
            float y = ac[i] + bias[o];
            Y[((size_t)node * OC_total + o) * 8 + b] = y;
            psum[m * 4 + i] = (double)y;
            psq[m * 4 + i] = (double)y * (double)y;
        }
    }
#pragma unroll
    for (int d = 1; d < 16; d <<= 1) {
#pragma unroll
        for (int r = 0; r < 8; r++) {
            psum[r] += __shfl_xor(psum[r], d);
            psq[r] += __shfl_xor(psq[r], d);
        }
    }
    if (cl == 0) {
#pragma unroll
        for (int m = 0; m < 2; m++)
#pragma unroll
            for (int i = 0; i < 4; i++) {
                int ol = m * 16 + q * 4 + i;
                redd[wv][ol] = psum[m * 4 + i];
                redd[wv][32 + ol] = psq[m * 4 + i];
            }
    }
    __syncthreads();
    if (tid < 64) {
        double v = redd[0][tid] + redd[1][tid] + redd[2][tid] + redd[3][tid];
        if (tid < 32) atomicAdd(&bnsum[obase + tid], v);
        else atomicAdd(&bnsq[obase + tid - 32], v);
    }
}

// ---------------- BN finalize: scale/shift per channel ----------------
__global__ void bn_finalize(const double* __restrict__ bnsum, const double* __restrict__ bnsq,
                            const float* __restrict__ g, const float* __restrict__ be,
                            float* __restrict__ sc, float* __restrict__ sh, int OC) {
    int o = threadIdx.x;
    if (o < OC) {
        double cnt = (double)N2C * 8.0;
        double mean = bnsum[o] / cnt;
        double var = bnsq[o] / cnt - mean * mean;
        double rs = 1.0 / sqrt(var + 1e-5);
        double s = (double)g[o] * rs;
        sc[o] = (float)s;
        sh[o] = (float)((double)be[o] - mean * s);
    }
}

// ---------------- pool: out[b][o][m] = max_k relu(bn(Y3[pidx[m,k]][o][b])) ----------------
__global__ void pool_kernel(const float* __restrict__ Y3, const int* __restrict__ pidx,
                            const float* __restrict__ sc, const float* __restrict__ sh,
                            float* __restrict__ out) {
    int m = blockIdx.x;
    int tid = threadIdx.x;    // 512 = o*8+b
    int o = tid >> 3, b = tid & 7;
    float s = sc[o], h = sh[o];
    float mx = 0.f;           // relu outputs are >= 0
#pragma unroll
    for (int k = 0; k < 9; k++) {
        int j = pidx[m * 9 + k];                  // uniform
        float v = Y3[(size_t)j * 512 + tid];      // coalesced
        mx = fmaxf(mx, fmaxf(v * s + h, 0.f));
    }
    out[((size_t)b * 64 + o) * 3136 + m] = mx;
}

extern "C" void kernel_launch(void* const* d_in, const int* in_sizes, int n_in,
                              void* d_out, int out_size, void* d_ws, size_t ws_size,
                              hipStream_t stream) {
    const float* x    = (const float*)d_in[0];
    const int*   nbr1 = (const int*)d_in[1];
    const float* off1 = (const float*)d_in[2];
    const int*   nbr2 = (const int*)d_in[3];
    const float* off2 = (const float*)d_in[4];
    const int*   pidx = (const int*)d_in[5];
    const float* Wh   = (const float*)d_in[6];
    const float* bh   = (const float*)d_in[7];
    const float* Wo   = (const float*)d_in[8];
    const float* bo   = (const float*)d_in[9];
    const float* W1   = (const float*)d_in[10];
    const float* b1   = (const float*)d_in[11];
    const float* W2   = (const float*)d_in[12];
    const float* b2   = (const float*)d_in[13];
    const float* W3   = (const float*)d_in[14];
    const float* b3   = (const float*)d_in[15];
    const float* g1   = (const float*)d_in[16];
    const float* be1  = (const float*)d_in[17];
    const float* g2   = (const float*)d_in[18];
    const float* be2  = (const float*)d_in[19];
    const float* g3   = (const float*)d_in[20];
    const float* be3  = (const float*)d_in[21];

    char* ws = (char*)d_ws;
    size_t off = 0;
    auto alloc = [&](size_t bytes) -> void* {
        void* p = ws + off;
        off += (bytes + 255) & ~(size_t)255;
        return p;
    };
    float* X0 = (float*)alloc((size_t)N1C * 24 * 4);
    float* A1 = (float*)alloc((size_t)N2C * 81 * 4);
    float* A2 = (float*)alloc((size_t)N2C * 81 * 4);
    float* Y1 = (float*)alloc((size_t)N2C * 256 * 4);
    float* Y2 = (float*)alloc((size_t)N2C * 256 * 4);
    float* Y3 = (float*)alloc((size_t)N2C * 512 * 4);
    double* bnacc = (double*)alloc(256 * 8);
    float* scbuf = (float*)alloc(256 * 4);

    double* sum1 = bnacc;        double* sq1 = bnacc + 32;
    double* sum2 = bnacc + 64;   double* sq2 = bnacc + 96;
    double* sum3 = bnacc + 128;  double* sq3 = bnacc + 192;
    float* sc1 = scbuf;       float* sh1 = scbuf + 32;
    float* sc2 = scbuf + 64;  float* sh2 = scbuf + 96;
    float* sc3 = scbuf + 128; float* sh3 = scbuf + 192;

    hipMemsetAsync(bnacc, 0, 256 * 8, stream);
    transpose_x<<<N1C / 64, 256, 0, stream>>>(x, X0);
    mlp_kernel<<<(N2C * 9 + 255) / 256, 256, 0, stream>>>(off1, Wh, bh, Wo, bo, A1, N2C * 9);
    mlp_kernel<<<(N2C * 9 + 255) / 256, 256, 0, stream>>>(off2, Wh, bh, Wo, bo, A2, N2C * 9);

    conv_kernel<3><<<dim3(N2C / 8, 1), 256, 0, stream>>>(X0, nbr1, A1, W1, b1,
                                                         nullptr, nullptr, Y1, sum1, sq1, 32);
    bn_finalize<<<1, 64, 0, stream>>>(sum1, sq1, g1, be1, sc1, sh1, 32);

    conv_kernel<32><<<dim3(N2C / 8, 1), 256, 0, stream>>>(Y1, nbr2, A2, W2, b2,
                                                          sc1, sh1, Y2, sum2, sq2, 32);
    bn_finalize<<<1, 64, 0, stream>>>(sum2, sq2, g2, be2, sc2, sh2, 32);

    conv_kernel<32><<<dim3(N2C / 8, 2), 256, 0, stream>>>(Y2, nbr2, A2, W3, b3,
                                                          sc2, sh2, Y3, sum3, sq3, 64);
    bn_finalize<<<1, 64, 0, stream>>>(sum3, sq3, g3, be3, sc3, sh3, 64);

    pool_kernel<<<N3C, 512, 0, stream>>>(Y3, pidx, sc3, sh3, (float*)d_out);
}

// Round 2
// 326.735 us; speedup vs baseline: 1.7435x; 1.7435x over previous
//
#include <hip/hip_runtime.h>
#include <hip/hip_bf16.h>
#include <math.h>

#define N1C 50176
#define N2C 12544
#define N3C 3136

typedef __attribute__((ext_vector_type(8))) short bf16x8;
typedef __attribute__((ext_vector_type(4))) float f32x4;

__device__ __forceinline__ unsigned short f2bf(float f) {
    unsigned u = __builtin_bit_cast(unsigned, f);
    u += 0x7fffu + ((u >> 16) & 1u);
    return (unsigned short)(u >> 16);
}

// ---------------- transpose x (B,3,N1) -> X0 [n][c*8+b] ----------------
__global__ void transpose_x(const float* __restrict__ x, float* __restrict__ X0) {
    __shared__ float T[64][25];
    int n0 = blockIdx.x * 64;
    int tid = threadIdx.x;
    for (int r = tid; r < 24 * 64; r += 256) {
        int cb = r >> 6;          // b*3+c
        int nn = r & 63;
        T[nn][cb] = x[cb * N1C + n0 + nn];
    }
    __syncthreads();
    for (int w = tid; w < 64 * 24; w += 256) {
        int nn = w / 24;
        int cc = w - nn * 24;     // c*8+b
        int c = cc >> 3, b = cc & 7;
        X0[(n0 + nn) * 24 + cc] = T[nn][b * 3 + c];
    }
}

// ---------------- MLP: a[n][k][t] ----------------
__global__ void mlp_kernel(const float* __restrict__ off,
                           const float* __restrict__ Wh, const float* __restrict__ bh,
                           const float* __restrict__ Wo, const float* __restrict__ bo,
                           float* __restrict__ A, int total) {
    int idx = blockIdx.x * 256 + threadIdx.x;
    if (idx >= total) return;
    float o0 = off[idx * 2], o1 = off[idx * 2 + 1];
    float out[9];
#pragma unroll
    for (int t = 0; t < 9; t++) out[t] = bo[t];
#pragma unroll
    for (int h = 0; h < 32; h++) {
        float hv = fmaxf(o0 * Wh[h] + o1 * Wh[32 + h] + bh[h], 0.f);
#pragma unroll
        for (int t = 0; t < 9; t++) out[t] += hv * Wo[h * 9 + t];
    }
#pragma unroll
    for (int t = 0; t < 9; t++) A[idx * 9 + t] = out[t];
}

// ---------------- pad W into fragment-major bf16 ----------------
// Wp index: (((g*KT + kt)*4 + q)*32 + o')*8 + j   with k' = kt*32+q*8+j = t*CIN+c
__global__ void pad_w(const float* __restrict__ W, unsigned short* __restrict__ Wp,
                      int OC, int CIN, int KT, int total) {
    int i = blockIdx.x * 256 + threadIdx.x;
    if (i >= total) return;
    int j = i & 7;
    int op = (i >> 3) & 31;
    int q = (i >> 8) & 3;
    int kt = (i >> 10) % KT;
    int g = i / (KT * 1024);
    int kp = kt * 32 + q * 8 + j;
    int t = kp / CIN, c = kp - t * CIN;
    int o = g * 32 + op;
    float v = (t < 9 && o < OC) ? W[(o * CIN + c) * 9 + t] : 0.f;
    Wp[i] = f2bf(v);
}

// ---------------- fused interp-conv ----------------
// Xin: [Nin][CIN*8]  (bn(scale,shift)+relu applied on gather if HAS_BN)
// Y:   [N2][OC_total][8]  (pre-BN);  bnsum/bnsq: per-o partials (double)
template <int CIN, bool HAS_BN>
__global__ __launch_bounds__(256, 4)
void conv_kernel(const float* __restrict__ Xin,
                 const int* __restrict__ nbr,
                 const float* __restrict__ A,
                 const unsigned short* __restrict__ Wp,  // fragment-major bf16
                 const float* __restrict__ bias,
                 const float* __restrict__ bnsc,
                 const float* __restrict__ bnsh,
                 float* __restrict__ Y,
                 double* __restrict__ bnsum,
                 double* __restrict__ bnsq,
                 int OC_total) {
    constexpr int KREAL = 9 * CIN;
    constexpr int KROW = (KREAL + 31) & ~31;  // 32 (CIN=3) / 288 (CIN=32)
    constexpr int KT = KROW / 32;
    constexpr int KSTR = KROW + 8;            // +16B: break power-of-2 bank stride
    constexpr int CB = CIN * 8;

    __shared__ alignas(16) short S[64 * KSTR];

    int tid = threadIdx.x;
    int obase = blockIdx.y * 32;
    int tile = blockIdx.x;
    int n0 = tile * 8;

    if constexpr (KROW != KREAL) {            // only CIN=3: zero pad slots
        for (int i = tid; i < 64 * KSTR; i += 256) S[i] = 0;
        __syncthreads();
    }

    // ---- s phase: S[col][t*CIN+c] = sum_k a[n,k,t] * feat(c,b,k) ----
    if constexpr (CIN == 3) {
        if (tid < 192) {
            int nsub = tid / 24;
            int cb = tid - nsub * 24;
            int c = cb >> 3, b = cb & 7;
            int n = n0 + nsub;
            const float* Ar = A + n * 81;
            float s[9];
#pragma unroll
            for (int t = 0; t < 9; t++) s[t] = 0.f;
#pragma unroll
            for (int k = 0; k < 9; k++) {
                int j = nbr[n * 9 + k];
                float f = Xin[j * CB + cb];
#pragma unroll
                for (int t = 0; t < 9; t++) s[t] = fmaf(Ar[k * 9 + t], f, s[t]);
            }
            int col = nsub * 8 + b;
#pragma unroll
            for (int t = 0; t < 9; t++) S[col * KSTR + t * CIN + c] = (short)f2bf(s[t]);
        }
    } else {
        int c = tid >> 3, b = tid & 7;
        float sc = 1.f, sh = 0.f;
        if (HAS_BN) { sc = bnsc[c]; sh = bnsh[c]; }
        const int* nb = nbr + n0 * 9;
        float f[9];
#pragma unroll
        for (int k = 0; k < 9; k++) f[k] = Xin[nb[k] * CB + tid];
#pragma unroll 1
        for (int nsub = 0; nsub < 8; nsub++) {
            // prefetch next node's rows while computing this one's FMAs
            float fn[9];
            int nn = (nsub < 7) ? nsub + 1 : 7;
#pragma unroll
            for (int k = 0; k < 9; k++) fn[k] = Xin[nb[nn * 9 + k] * CB + tid];
            const float* Ar = A + (n0 + nsub) * 81;
            float s[9];
#pragma unroll
            for (int t = 0; t < 9; t++) s[t] = 0.f;
#pragma unroll
            for (int k = 0; k < 9; k++) {
                float v = f[k];
                if (HAS_BN) v = fmaxf(fmaf(v, sc, sh), 0.f);
#pragma unroll
                for (int t = 0; t < 9; t++) s[t] = fmaf(Ar[k * 9 + t], v, s[t]);
            }
            int col = nsub * 8 + b;
#pragma unroll
            for (int t = 0; t < 9; t++) S[col * KSTR + t * CIN + c] = (short)f2bf(s[t]);
#pragma unroll
            for (int k = 0; k < 9; k++) f[k] = fn[k];
        }
    }
    __syncthreads();

    // ---- MFMA: Y[o][col] = Wp[o][k'] * S[col][k'] ----
    int lane = tid & 63;
    int wv = tid >> 6;
    int q = lane >> 4;
    int cl = lane & 15;
    int colg = wv * 16 + cl;

    const bf16x8* wf = (const bf16x8*)Wp + (size_t)blockIdx.y * (KT * 4 * 32);
    f32x4 acc0 = {0.f, 0.f, 0.f, 0.f};
    f32x4 acc1 = {0.f, 0.f, 0.f, 0.f};
#pragma unroll
    for (int kt = 0; kt < KT; kt++) {
        bf16x8 bfr = *(const bf16x8*)&S[colg * KSTR + kt * 32 + q * 8];
        bf16x8 a0 = wf[(kt * 4 + q) * 32 + cl];
        bf16x8 a1 = wf[(kt * 4 + q) * 32 + cl + 16];
        acc0 = __builtin_amdgcn_mfma_f32_16x16x32_bf16(a0, bfr, acc0, 0, 0, 0);
        acc1 = __builtin_amdgcn_mfma_f32_16x16x32_bf16(a1, bfr, acc1, 0, 0, 0);
    }

    __syncthreads();   // all S reads done -> reuse S as reduction buffer
    double (*redd)[64] = (double(*)[64])S;

    // ---- epilogue: bias, store, BN partials (double) ----
    int node = n0 + (colg >> 3);
    int b = colg & 7;
    double psum[8], psq[8];
#pragma unroll
    for (int m = 0; m < 2; m++) {
        f32x4 ac = m ? acc1 : acc0;
#pragma unroll
        for (int i = 0; i < 4; i++) {
            int o = obase + m * 16 + q * 4 + i;
            float y = ac[i] + bias[o];
            Y[((size_t)node * OC_total + o) * 8 + b] = y;
            psum[m * 4 + i] = (double)y;
            psq[m * 4 + i] = (double)y * (double)y;
        }
    }
#pragma unroll
    for (int d = 1; d < 16; d <<= 1) {
#pragma unroll
        for (int r = 0; r < 8; r++) {
            psum[r] += __shfl_xor(psum[r], d);
            psq[r] += __shfl_xor(psq[r], d);
        }
    }
    if (cl == 0) {
#pragma unroll
        for (int m = 0; m < 2; m++)
#pragma unroll
            for (int i = 0; i < 4; i++) {
                int ol = m * 16 + q * 4 + i;
                redd[wv][ol] = psum[m * 4 + i];
                redd[wv][32 + ol] = psq[m * 4 + i];
            }
    }
    __syncthreads();
    if (tid < 64) {
        double v = redd[0][tid] + redd[1][tid] + redd[2][tid] + redd[3][tid];
        if (tid < 32) atomicAdd(&bnsum[obase + tid], v);
        else atomicAdd(&bnsq[obase + tid - 32], v);
    }
}

// ---------------- BN finalize: scale/shift per channel ----------------
__global__ void bn_finalize(const double* __restrict__ bnsum, const double* __restrict__ bnsq,
                            const float* __restrict__ g, const float* __restrict__ be,
                            float* __restrict__ sc, float* __restrict__ sh, int OC) {
    int o = threadIdx.x;
    if (o < OC) {
        double cnt = (double)N2C * 8.0;
        double mean = bnsum[o] / cnt;
        double var = bnsq[o] / cnt - mean * mean;
        double rs = 1.0 / sqrt(var + 1e-5);
        double s = (double)g[o] * rs;
        sc[o] = (float)s;
        sh[o] = (float)((double)be[o] - mean * s);
    }
}

// ---------------- pool: out[b][o][m] = max_k relu(bn(Y3[pidx[m,k]][o][b])) ----------------
__global__ void pool_kernel(const float* __restrict__ Y3, const int* __restrict__ pidx,
                            const float* __restrict__ sc, const float* __restrict__ sh,
                            float* __restrict__ out) {
    int m = blockIdx.x;
    int tid = threadIdx.x;    // 512 = o*8+b
    int o = tid >> 3, b = tid & 7;
    float s = sc[o], h = sh[o];
    float mx = 0.f;           // relu outputs are >= 0
#pragma unroll
    for (int k = 0; k < 9; k++) {
        int j = pidx[m * 9 + k];                  // uniform
        float v = Y3[(size_t)j * 512 + tid];      // coalesced
        mx = fmaxf(mx, fmaxf(v * s + h, 0.f));
    }
    out[((size_t)b * 64 + o) * 3136 + m] = mx;
}

extern "C" void kernel_launch(void* const* d_in, const int* in_sizes, int n_in,
                              void* d_out, int out_size, void* d_ws, size_t ws_size,
                              hipStream_t stream) {
    const float* x    = (const float*)d_in[0];
    const int*   nbr1 = (const int*)d_in[1];
    const float* off1 = (const float*)d_in[2];
    const int*   nbr2 = (const int*)d_in[3];
    const float* off2 = (const float*)d_in[4];
    const int*   pidx = (const int*)d_in[5];
    const float* Wh   = (const float*)d_in[6];
    const float* bh   = (const float*)d_in[7];
    const float* Wo   = (const float*)d_in[8];
    const float* bo   = (const float*)d_in[9];
    const float* W1   = (const float*)d_in[10];
    const float* b1   = (const float*)d_in[11];
    const float* W2   = (const float*)d_in[12];
    const float* b2   = (const float*)d_in[13];
    const float* W3   = (const float*)d_in[14];
    const float* b3   = (const float*)d_in[15];
    const float* g1   = (const float*)d_in[16];
    const float* be1  = (const float*)d_in[17];
    const float* g2   = (const float*)d_in[18];
    const float* be2  = (const float*)d_in[19];
    const float* g3   = (const float*)d_in[20];
    const float* be3  = (const float*)d_in[21];

    char* ws = (char*)d_ws;
    size_t off = 0;
    auto alloc = [&](size_t bytes) -> void* {
        void* p = ws + off;
        off += (bytes + 255) & ~(size_t)255;
        return p;
    };
    float* X0 = (float*)alloc((size_t)N1C * 24 * 4);
    float* A1 = (float*)alloc((size_t)N2C * 81 * 4);
    float* A2 = (float*)alloc((size_t)N2C * 81 * 4);
    float* Y1 = (float*)alloc((size_t)N2C * 256 * 4);
    float* Y2 = (float*)alloc((size_t)N2C * 256 * 4);
    float* Y3 = (float*)alloc((size_t)N2C * 512 * 4);
    unsigned short* W1p = (unsigned short*)alloc(32 * 32 * 2);
    unsigned short* W2p = (unsigned short*)alloc(32 * 288 * 2);
    unsigned short* W3p = (unsigned short*)alloc(64 * 288 * 2);
    double* bnacc = (double*)alloc(256 * 8);
    float* scbuf = (float*)alloc(256 * 4);

    double* sum1 = bnacc;        double* sq1 = bnacc + 32;
    double* sum2 = bnacc + 64;   double* sq2 = bnacc + 96;
    double* sum3 = bnacc + 128;  double* sq3 = bnacc + 192;
    float* sc1 = scbuf;       float* sh1 = scbuf + 32;
    float* sc2 = scbuf + 64;  float* sh2 = scbuf + 96;
    float* sc3 = scbuf + 128; float* sh3 = scbuf + 192;

    hipMemsetAsync(bnacc, 0, 256 * 8, stream);
    transpose_x<<<N1C / 64, 256, 0, stream>>>(x, X0);
    mlp_kernel<<<(N2C * 9 + 255) / 256, 256, 0, stream>>>(off1, Wh, bh, Wo, bo, A1, N2C * 9);
    mlp_kernel<<<(N2C * 9 + 255) / 256, 256, 0, stream>>>(off2, Wh, bh, Wo, bo, A2, N2C * 9);
    pad_w<<<(32 * 32 + 255) / 256, 256, 0, stream>>>(W1, W1p, 32, 3, 1, 32 * 32);
    pad_w<<<(32 * 288 + 255) / 256, 256, 0, stream>>>(W2, W2p, 32, 32, 9, 32 * 288);
    pad_w<<<(64 * 288 + 255) / 256, 256, 0, stream>>>(W3, W3p, 64, 32, 9, 64 * 288);

    conv_kernel<3, false><<<dim3(N2C / 8, 1), 256, 0, stream>>>(X0, nbr1, A1, W1p, b1,
                                                                nullptr, nullptr, Y1, sum1, sq1, 32);
    bn_finalize<<<1, 64, 0, stream>>>(sum1, sq1, g1, be1, sc1, sh1, 32);

    conv_kernel<32, true><<<dim3(N2C / 8, 1), 256, 0, stream>>>(Y1, nbr2, A2, W2p, b2,
                                                                sc1, sh1, Y2, sum2, sq2, 32);
    bn_finalize<<<1, 64, 0, stream>>>(sum2, sq2, g2, be2, sc2, sh2, 32);

    conv_kernel<32, true><<<dim3(N2C / 8, 2), 256, 0, stream>>>(Y2, nbr2, A2, W3p, b3,
                                                                sc2, sh2, Y3, sum3, sq3, 64);
    bn_finalize<<<1, 64, 0, stream>>>(sum3, sq3, g3, be3, sc3, sh3, 64);

    pool_kernel<<<N3C, 512, 0, stream>>>(Y3, pidx, sc3, sh3, (float*)d_out);
}

// Round 3
// 322.998 us; speedup vs baseline: 1.7637x; 1.0116x over previous
//
#include <hip/hip_runtime.h>
#include <math.h>

#define N1C 50176
#define N2C 12544
#define N3C 3136

typedef __attribute__((ext_vector_type(8))) short bf16x8;
typedef __attribute__((ext_vector_type(4))) float f32x4;

__device__ __forceinline__ unsigned short f2bf(float f) {
    unsigned u = __builtin_bit_cast(unsigned, f);
    u += 0x7fffu + ((u >> 16) & 1u);
    return (unsigned short)(u >> 16);
}
__device__ __forceinline__ float bf2f(unsigned short u) {
    return __builtin_bit_cast(float, (unsigned)u << 16);
}

// ---------------- transpose x (B,3,N1) -> X0b bf16 [n][b*3+c] ----------------
__global__ void transpose_x(const float* __restrict__ x, unsigned short* __restrict__ X0) {
    __shared__ float T[64][25];
    int n0 = blockIdx.x * 64;
    int tid = threadIdx.x;
    for (int r = tid; r < 24 * 64; r += 256) {
        int cb = r >> 6;          // flat (b*3+c) in source [8][3][N1]
        int nn = r & 63;
        T[nn][cb] = x[cb * N1C + n0 + nn];
    }
    __syncthreads();
    for (int w = tid; w < 64 * 24; w += 256) {
        int nn = w / 24;
        int u = w - nn * 24;      // u = b*3+c
        X0[(n0 + nn) * 24 + u] = f2bf(T[nn][u]);
    }
}

// ---------------- MLP: a[n][k][t] ----------------
__global__ void mlp_kernel(const float* __restrict__ off,
                           const float* __restrict__ Wh, const float* __restrict__ bh,
                           const float* __restrict__ Wo, const float* __restrict__ bo,
                           float* __restrict__ A, int total) {
    int idx = blockIdx.x * 256 + threadIdx.x;
    if (idx >= total) return;
    float o0 = off[idx * 2], o1 = off[idx * 2 + 1];
    float out[9];
#pragma unroll
    for (int t = 0; t < 9; t++) out[t] = bo[t];
#pragma unroll
    for (int h = 0; h < 32; h++) {
        float hv = fmaxf(o0 * Wh[h] + o1 * Wh[32 + h] + bh[h], 0.f);
#pragma unroll
        for (int t = 0; t < 9; t++) out[t] += hv * Wo[h * 9 + t];
    }
#pragma unroll
    for (int t = 0; t < 9; t++) A[idx * 9 + t] = out[t];
}

// ---------------- pad W into fragment-major bf16 ----------------
// Wp chunk index: (((g*KT + kt)*4 + q)*32 + o')*8 + j, k' = kt*32+q*8+j = t*CIN+c
__global__ void pad_w(const float* __restrict__ W, unsigned short* __restrict__ Wp,
                      int OC, int CIN, int KT, int total) {
    int i = blockIdx.x * 256 + threadIdx.x;
    if (i >= total) return;
    int j = i & 7;
    int op = (i >> 3) & 31;
    int q = (i >> 8) & 3;
    int kt = (i >> 10) % KT;
    int g = i / (KT * 1024);
    int kp = kt * 32 + q * 8 + j;
    int t = kp / CIN, c = kp - t * CIN;
    int o = g * 32 + op;
    float v = (t < 9 && o < OC) ? W[(o * CIN + c) * 9 + t] : 0.f;
    Wp[i] = f2bf(v);
}

// ---------------- layer-1 gather+weight: S1[(n*8+b)*32 + t*3+c] ----------------
// pad slots k'=27..31 pre-zeroed by memset
__global__ __launch_bounds__(256, 8)
void s1_kernel(const unsigned short* __restrict__ X0, const int* __restrict__ nbr,
               const float* __restrict__ A, unsigned short* __restrict__ S1) {
    int idx = blockIdx.x * 256 + threadIdx.x;    // n*24 + u
    if (idx >= N2C * 24) return;
    int n = idx / 24, u = idx - n * 24;
    int b = u / 3, c = u - b * 3;
    const int* nb = nbr + n * 9;
    int j[9];
#pragma unroll
    for (int k = 0; k < 9; k++) j[k] = nb[k];
    float f[9];
#pragma unroll
    for (int k = 0; k < 9; k++) f[k] = bf2f(X0[j[k] * 24 + u]);
    const float* Ar = A + n * 81;
    float s[9];
#pragma unroll
    for (int t = 0; t < 9; t++) s[t] = 0.f;
#pragma unroll
    for (int k = 0; k < 9; k++)
#pragma unroll
        for (int t = 0; t < 9; t++) s[t] = fmaf(Ar[k * 9 + t], f[k], s[t]);
    unsigned short* dst = S1 + ((size_t)n * 8 + b) * 32 + c;
#pragma unroll
    for (int t = 0; t < 9; t++) dst[t * 3] = f2bf(s[t]);
}

// ---------------- layer-2/3 gather+weight: S[(n*8+b)*288 + t*32+c] ----------------
// thread = (b,c): tid = b*32+c; gather Yb[j*256 + tid] coalesced bf16
__global__ __launch_bounds__(256, 8)
void s32_kernel(const unsigned short* __restrict__ Yb, const int* __restrict__ nbr,
                const float* __restrict__ A,
                const float* __restrict__ bnsc, const float* __restrict__ bnsh,
                unsigned short* __restrict__ S) {
    int n = blockIdx.x;
    int tid = threadIdx.x;
    int c = tid & 31, b = tid >> 5;
    float sc = bnsc[c], sh = bnsh[c];
    const int* nb = nbr + n * 9;
    float f[9];
#pragma unroll
    for (int k = 0; k < 9; k++) f[k] = bf2f(Yb[(size_t)nb[k] * 256 + tid]);
    const float* Ar = A + n * 81;
    float s[9];
#pragma unroll
    for (int t = 0; t < 9; t++) s[t] = 0.f;
#pragma unroll
    for (int k = 0; k < 9; k++) {
        float v = fmaxf(fmaf(f[k], sc, sh), 0.f);
#pragma unroll
        for (int t = 0; t < 9; t++) s[t] = fmaf(Ar[k * 9 + t], v, s[t]);
    }
    unsigned short* dst = S + ((size_t)n * 8 + b) * 288 + c;
#pragma unroll
    for (int t = 0; t < 9; t++) dst[t * 32] = f2bf(s[t]);
}

// ---------------- GEMM: Y[col][o] = Wp[o][k'] * S[col][k'] ----------------
template <int KROW, int MW>   // MW = OC/16
__global__ __launch_bounds__(256, 4)
void gemm_kernel(const unsigned short* __restrict__ S,
                 const unsigned short* __restrict__ Wp,
                 const float* __restrict__ bias,
                 unsigned short* __restrict__ Yb,
                 double* __restrict__ bnsum, double* __restrict__ bnsq) {
    constexpr int OC = MW * 16;
    constexpr int KT = KROW / 32;
    constexpr int KSTR = KROW + 8;
    constexpr int CH16 = KROW / 8;      // bf16x8 chunks per row
    __shared__ alignas(16) short Sl[64 * KSTR];

    int tid = threadIdx.x;
    int tile = blockIdx.x;

    // stage 64 cols of S, coalesced (tile is contiguous 64*KROW*2 bytes)
    const bf16x8* Sg = (const bf16x8*)(S + (size_t)tile * 64 * KROW);
    for (int i = tid; i < 64 * CH16; i += 256) {
        int row = i / CH16;
        int kk = (i - row * CH16) * 8;
        *(bf16x8*)&Sl[row * KSTR + kk] = Sg[i];
    }
    __syncthreads();

    int lane = tid & 63, wv = tid >> 6, q = lane >> 4, cl = lane & 15;
    int colg = wv * 16 + cl;

    const bf16x8* wf = (const bf16x8*)Wp;
    f32x4 acc[MW];
#pragma unroll
    for (int m = 0; m < MW; m++) acc[m] = (f32x4){0.f, 0.f, 0.f, 0.f};
#pragma unroll
    for (int kt = 0; kt < KT; kt++) {
        bf16x8 bfr = *(const bf16x8*)&Sl[colg * KSTR + kt * 32 + q * 8];
#pragma unroll
        for (int m = 0; m < MW; m++) {
            const bf16x8* wg = wf + (m >> 1) * (KT * 128);
            bf16x8 am = wg[(kt * 4 + q) * 32 + cl + (m & 1) * 16];
            acc[m] = __builtin_amdgcn_mfma_f32_16x16x32_bf16(am, bfr, acc[m], 0, 0, 0);
        }
    }
    __syncthreads();            // S reads done -> reuse LDS for reduction
    double (*redd)[2 * OC] = (double(*)[2 * OC])Sl;

    int C = tile * 64 + colg;   // global col = n*8+b
    float yv[4 * MW];
#pragma unroll
    for (int m = 0; m < MW; m++)
#pragma unroll
        for (int i = 0; i < 4; i++) {
            int o = m * 16 + q * 4 + i;
            float y = acc[m][i] + bias[o];
            yv[m * 4 + i] = y;
            Yb[(size_t)C * OC + o] = f2bf(y);
        }
    // per-register butterfly keeps only 2 doubles live
#pragma unroll
    for (int r = 0; r < 4 * MW; r++) {
        double ps = (double)yv[r];
        double pq = (double)yv[r] * (double)yv[r];
#pragma unroll
        for (int d = 1; d < 16; d <<= 1) {
            ps += __shfl_xor(ps, d);
            pq += __shfl_xor(pq, d);
        }
        if (cl == 0) {
            int o = (r >> 2) * 16 + q * 4 + (r & 3);
            redd[wv][o] = ps;
            redd[wv][OC + o] = pq;
        }
    }
    __syncthreads();
    if (tid < 2 * OC) {
        double v = redd[0][tid] + redd[1][tid] + redd[2][tid] + redd[3][tid];
        if (tid < OC) atomicAdd(&bnsum[tid], v);
        else atomicAdd(&bnsq[tid - OC], v);
    }
}

// ---------------- BN finalize ----------------
__global__ void bn_finalize(const double* __restrict__ bnsum, const double* __restrict__ bnsq,
                            const float* __restrict__ g, const float* __restrict__ be,
                            float* __restrict__ sc, float* __restrict__ sh, int OC) {
    int o = threadIdx.x;
    if (o < OC) {
        double cnt = (double)N2C * 8.0;
        double mean = bnsum[o] / cnt;
        double var = bnsq[o] / cnt - mean * mean;
        double rs = 1.0 / sqrt(var + 1e-5);
        double s = (double)g[o] * rs;
        sc[o] = (float)s;
        sh[o] = (float)((double)be[o] - mean * s);
    }
}

// ---------------- pool: 16 m per block; lane writes a full 64B line ----------------
__global__ __launch_bounds__(512, 4)
void pool_kernel(const unsigned short* __restrict__ Y3, const int* __restrict__ pidx,
                 const float* __restrict__ sc, const float* __restrict__ sh,
                 float* __restrict__ out) {
    int m0 = blockIdx.x * 16;
    int tid = threadIdx.x;      // b*64 + o
    int o = tid & 63;
    float s = sc[o], h = sh[o];
    float mx[16];
    int jn[9];
#pragma unroll
    for (int k = 0; k < 9; k++) jn[k] = pidx[m0 * 9 + k];
#pragma unroll 1
    for (int mi = 0; mi < 16; mi++) {
        int jc[9];
#pragma unroll
        for (int k = 0; k < 9; k++) jc[k] = jn[k];
        if (mi < 15) {
#pragma unroll
            for (int k = 0; k < 9; k++) jn[k] = pidx[(m0 + mi + 1) * 9 + k];
        }
        float v0 = 0.f;
#pragma unroll
        for (int k = 0; k < 9; k++) {
            float v = bf2f(Y3[(size_t)jc[k] * 512 + tid]);
            v0 = fmaxf(v0, fmaf(v, s, h));
        }
        mx[mi] = fmaxf(v0, 0.f);
    }
    float* op = out + (size_t)tid * 3136 + m0;
#pragma unroll
    for (int mi = 0; mi < 16; mi++) op[mi] = mx[mi];
}

extern "C" void kernel_launch(void* const* d_in, const int* in_sizes, int n_in,
                              void* d_out, int out_size, void* d_ws, size_t ws_size,
                              hipStream_t stream) {
    const float* x    = (const float*)d_in[0];
    const int*   nbr1 = (const int*)d_in[1];
    const float* off1 = (const float*)d_in[2];
    const int*   nbr2 = (const int*)d_in[3];
    const float* off2 = (const float*)d_in[4];
    const int*   pidx = (const int*)d_in[5];
    const float* Wh   = (const float*)d_in[6];
    const float* bh   = (const float*)d_in[7];
    const float* Wo   = (const float*)d_in[8];
    const float* bo   = (const float*)d_in[9];
    const float* W1   = (const float*)d_in[10];
    const float* b1   = (const float*)d_in[11];
    const float* W2   = (const float*)d_in[12];
    const float* b2   = (const float*)d_in[13];
    const float* W3   = (const float*)d_in[14];
    const float* b3   = (const float*)d_in[15];
    const float* g1   = (const float*)d_in[16];
    const float* be1  = (const float*)d_in[17];
    const float* g2   = (const float*)d_in[18];
    const float* be2  = (const float*)d_in[19];
    const float* g3   = (const float*)d_in[20];
    const float* be3  = (const float*)d_in[21];

    char* ws = (char*)d_ws;
    size_t off = 0;
    auto alloc = [&](size_t bytes) -> void* {
        void* p = ws + off;
        off += (bytes + 255) & ~(size_t)255;
        return p;
    };
    // Big shared S buffer (57.8 MB): used as S2/S3 operand for layers 2&3.
    // S1 (6.4MB), X0b (2.4MB), A1 (4.1MB) alias its head — all dead before
    // the first s32_kernel writes S in full.
    unsigned short* S   = (unsigned short*)alloc((size_t)N2C * 8 * 288 * 2);
    unsigned short* S1  = S;                                           // [0, 6.42MB)
    unsigned short* X0b = (unsigned short*)((char*)S + (8u << 20));    // 2.41MB
    float*          A1  = (float*)((char*)S + (12u << 20));            // 4.07MB
    float*          A2  = (float*)alloc((size_t)N2C * 81 * 4);
    // Y buffers: Y3b (12.8MB) aliases [Y1b | Y2b] (each dead before Y3 write)
    unsigned short* Ybuf = (unsigned short*)alloc((size_t)N2C * 8 * 64 * 2);
    unsigned short* Y1b = Ybuf;
    unsigned short* Y2b = Ybuf + (size_t)N2C * 8 * 32;
    unsigned short* Y3b = Ybuf;
    unsigned short* W1p = (unsigned short*)alloc(32 * 32 * 2);
    unsigned short* W2p = (unsigned short*)alloc(32 * 288 * 2);
    unsigned short* W3p = (unsigned short*)alloc(64 * 288 * 2);
    double* bnacc = (double*)alloc(256 * 8);
    float*  scbuf = (float*)alloc(256 * 4);

    double* sum1 = bnacc;        double* sq1 = bnacc + 32;
    double* sum2 = bnacc + 64;   double* sq2 = bnacc + 96;
    double* sum3 = bnacc + 128;  double* sq3 = bnacc + 192;
    float* sc1 = scbuf;       float* sh1 = scbuf + 32;
    float* sc2 = scbuf + 64;  float* sh2 = scbuf + 96;
    float* sc3 = scbuf + 128; float* sh3 = scbuf + 192;

    hipMemsetAsync(bnacc, 0, 256 * 8, stream);
    hipMemsetAsync(S1, 0, (size_t)N2C * 8 * 32 * 2, stream);   // zero K-pad slots

    transpose_x<<<N1C / 64, 256, 0, stream>>>(x, X0b);
    mlp_kernel<<<(N2C * 9 + 255) / 256, 256, 0, stream>>>(off1, Wh, bh, Wo, bo, A1, N2C * 9);
    mlp_kernel<<<(N2C * 9 + 255) / 256, 256, 0, stream>>>(off2, Wh, bh, Wo, bo, A2, N2C * 9);
    pad_w<<<(32 * 32 + 255) / 256, 256, 0, stream>>>(W1, W1p, 32, 3, 1, 32 * 32);
    pad_w<<<(32 * 288 + 255) / 256, 256, 0, stream>>>(W2, W2p, 32, 32, 9, 32 * 288);
    pad_w<<<(64 * 288 + 255) / 256, 256, 0, stream>>>(W3, W3p, 64, 32, 9, 64 * 288);

    // ---- layer 1 ----
    s1_kernel<<<N2C * 24 / 256, 256, 0, stream>>>(X0b, nbr1, A1, S1);
    gemm_kernel<32, 2><<<N2C * 8 / 64, 256, 0, stream>>>(S1, W1p, b1, Y1b, sum1, sq1);
    bn_finalize<<<1, 64, 0, stream>>>(sum1, sq1, g1, be1, sc1, sh1, 32);

    // ---- layer 2 ----
    s32_kernel<<<N2C, 256, 0, stream>>>(Y1b, nbr2, A2, sc1, sh1, S);
    gemm_kernel<288, 2><<<N2C * 8 / 64, 256, 0, stream>>>(S, W2p, b2, Y2b, sum2, sq2);
    bn_finalize<<<1, 64, 0, stream>>>(sum2, sq2, g2, be2, sc2, sh2, 32);

    // ---- layer 3 (single gather pass even though OC=64) ----
    s32_kernel<<<N2C, 256, 0, stream>>>(Y2b, nbr2, A2, sc2, sh2, S);
    gemm_kernel<288, 4><<<N2C * 8 / 64, 256, 0, stream>>>(S, W3p, b3, Y3b, sum3, sq3);
    bn_finalize<<<1, 64, 0, stream>>>(sum3, sq3, g3, be3, sc3, sh3, 64);

    pool_kernel<<<N3C / 16, 512, 0, stream>>>(Y3b, pidx, sc3, sh3, (float*)d_out);
}

// Round 4
// 268.999 us; speedup vs baseline: 2.1177x; 1.2007x over previous
//
#include <hip/hip_runtime.h>
#include <math.h>

#define N1C 50176
#define N2C 12544
#define N3C 3136
#define NT_TILES (N2C * 8 / 64)   // 1568 gemm tiles

typedef __attribute__((ext_vector_type(8))) short bf16x8;
typedef __attribute__((ext_vector_type(4))) float f32x4;

__device__ __forceinline__ unsigned short f2bf(float f) {
    unsigned u = __builtin_bit_cast(unsigned, f);
    u += 0x7fffu + ((u >> 16) & 1u);
    return (unsigned short)(u >> 16);
}
__device__ __forceinline__ float bf2f(unsigned short u) {
    return __builtin_bit_cast(float, (unsigned)u << 16);
}

// ---------------- transpose x (B,3,N1) -> X0b bf16 [n][b*3+c] ----------------
__global__ void transpose_x(const float* __restrict__ x, unsigned short* __restrict__ X0) {
    __shared__ float T[64][25];
    int n0 = blockIdx.x * 64;
    int tid = threadIdx.x;
    for (int r = tid; r < 24 * 64; r += 256) {
        int cb = r >> 6;          // flat (b*3+c) in source [8][3][N1]
        int nn = r & 63;
        T[nn][cb] = x[cb * N1C + n0 + nn];
    }
    __syncthreads();
    for (int w = tid; w < 64 * 24; w += 256) {
        int nn = w / 24;
        int u = w - nn * 24;      // u = b*3+c
        X0[(n0 + nn) * 24 + u] = f2bf(T[nn][u]);
    }
}

// ---------------- MLP: a[n][k][t] ----------------
__global__ void mlp_kernel(const float* __restrict__ off,
                           const float* __restrict__ Wh, const float* __restrict__ bh,
                           const float* __restrict__ Wo, const float* __restrict__ bo,
                           float* __restrict__ A, int total) {
    int idx = blockIdx.x * 256 + threadIdx.x;
    if (idx >= total) return;
    float o0 = off[idx * 2], o1 = off[idx * 2 + 1];
    float out[9];
#pragma unroll
    for (int t = 0; t < 9; t++) out[t] = bo[t];
#pragma unroll
    for (int h = 0; h < 32; h++) {
        float hv = fmaxf(o0 * Wh[h] + o1 * Wh[32 + h] + bh[h], 0.f);
#pragma unroll
        for (int t = 0; t < 9; t++) out[t] += hv * Wo[h * 9 + t];
    }
#pragma unroll
    for (int t = 0; t < 9; t++) A[idx * 9 + t] = out[t];
}

// ---------------- pad W into fragment-major bf16 ----------------
// Wp chunk index: (((g*KT + kt)*4 + q)*32 + o')*8 + j, k' = kt*32+q*8+j = t*CIN+c
__global__ void pad_w(const float* __restrict__ W, unsigned short* __restrict__ Wp,
                      int OC, int CIN, int KT, int total) {
    int i = blockIdx.x * 256 + threadIdx.x;
    if (i >= total) return;
    int j = i & 7;
    int op = (i >> 3) & 31;
    int q = (i >> 8) & 3;
    int kt = (i >> 10) % KT;
    int g = i / (KT * 1024);
    int kp = kt * 32 + q * 8 + j;
    int t = kp / CIN, c = kp - t * CIN;
    int o = g * 32 + op;
    float v = (t < 9 && o < OC) ? W[(o * CIN + c) * 9 + t] : 0.f;
    Wp[i] = f2bf(v);
}

// ---------------- layer-1 gather+weight: S1[(n*8+b)*32 + t*3+c] ----------------
// pad slots k'=27..31 pre-zeroed by memset
__global__ __launch_bounds__(256, 8)
void s1_kernel(const unsigned short* __restrict__ X0, const int* __restrict__ nbr,
               const float* __restrict__ A, unsigned short* __restrict__ S1) {
    int idx = blockIdx.x * 256 + threadIdx.x;    // n*24 + u
    if (idx >= N2C * 24) return;
    int n = idx / 24, u = idx - n * 24;
    int b = u / 3, c = u - b * 3;
    const int* nb = nbr + n * 9;
    int j[9];
#pragma unroll
    for (int k = 0; k < 9; k++) j[k] = nb[k];
    float f[9];
#pragma unroll
    for (int k = 0; k < 9; k++) f[k] = bf2f(X0[j[k] * 24 + u]);
    const float* Ar = A + n * 81;
    float s[9];
#pragma unroll
    for (int t = 0; t < 9; t++) s[t] = 0.f;
#pragma unroll
    for (int k = 0; k < 9; k++)
#pragma unroll
        for (int t = 0; t < 9; t++) s[t] = fmaf(Ar[k * 9 + t], f[k], s[t]);
    unsigned short* dst = S1 + ((size_t)n * 8 + b) * 32 + c;
#pragma unroll
    for (int t = 0; t < 9; t++) dst[t * 3] = f2bf(s[t]);
}

// ---------------- layer-2/3 gather+weight: S[(n*8+b)*288 + t*32+c] ----------------
// thread = (b,c): tid = b*32+c; gather Yb[j*256 + tid] coalesced bf16
__global__ __launch_bounds__(256, 8)
void s32_kernel(const unsigned short* __restrict__ Yb, const int* __restrict__ nbr,
                const float* __restrict__ A,
                const float* __restrict__ bnsc, const float* __restrict__ bnsh,
                unsigned short* __restrict__ S) {
    int n = blockIdx.x;
    int tid = threadIdx.x;
    int c = tid & 31, b = tid >> 5;
    float sc = bnsc[c], sh = bnsh[c];
    const int* nb = nbr + n * 9;
    float f[9];
#pragma unroll
    for (int k = 0; k < 9; k++) f[k] = bf2f(Yb[(size_t)nb[k] * 256 + tid]);
    const float* Ar = A + n * 81;
    float s[9];
#pragma unroll
    for (int t = 0; t < 9; t++) s[t] = 0.f;
#pragma unroll
    for (int k = 0; k < 9; k++) {
        float v = fmaxf(fmaf(f[k], sc, sh), 0.f);
#pragma unroll
        for (int t = 0; t < 9; t++) s[t] = fmaf(Ar[k * 9 + t], v, s[t]);
    }
    unsigned short* dst = S + ((size_t)n * 8 + b) * 288 + c;
#pragma unroll
    for (int t = 0; t < 9; t++) dst[t * 32] = f2bf(s[t]);
}

// ---------------- GEMM: Y[col][o] = Wp[o][k'] * S[col][k'] ----------------
// BN partials per block -> Part[tile][2*OC] (no atomics; reduced by bn_reduce)
template <int KROW, int MW>   // MW = OC/16
__global__ __launch_bounds__(256, 4)
void gemm_kernel(const unsigned short* __restrict__ S,
                 const unsigned short* __restrict__ Wp,
                 const float* __restrict__ bias,
                 unsigned short* __restrict__ Yb,
                 double* __restrict__ Part) {
    constexpr int OC = MW * 16;
    constexpr int KT = KROW / 32;
    constexpr int KSTR = KROW + 8;
    constexpr int CH16 = KROW / 8;      // bf16x8 chunks per row
    __shared__ alignas(16) short Sl[64 * KSTR];

    int tid = threadIdx.x;
    int tile = blockIdx.x;

    // stage 64 cols of S, coalesced (tile is contiguous 64*KROW*2 bytes)
    const bf16x8* Sg = (const bf16x8*)(S + (size_t)tile * 64 * KROW);
    for (int i = tid; i < 64 * CH16; i += 256) {
        int row = i / CH16;
        int kk = (i - row * CH16) * 8;
        *(bf16x8*)&Sl[row * KSTR + kk] = Sg[i];
    }
    __syncthreads();

    int lane = tid & 63, wv = tid >> 6, q = lane >> 4, cl = lane & 15;
    int colg = wv * 16 + cl;

    const bf16x8* wf = (const bf16x8*)Wp;
    f32x4 acc[MW];
#pragma unroll
    for (int m = 0; m < MW; m++) acc[m] = (f32x4){0.f, 0.f, 0.f, 0.f};
#pragma unroll
    for (int kt = 0; kt < KT; kt++) {
        bf16x8 bfr = *(const bf16x8*)&Sl[colg * KSTR + kt * 32 + q * 8];
#pragma unroll
        for (int m = 0; m < MW; m++) {
            const bf16x8* wg = wf + (m >> 1) * (KT * 128);
            bf16x8 am = wg[(kt * 4 + q) * 32 + cl + (m & 1) * 16];
            acc[m] = __builtin_amdgcn_mfma_f32_16x16x32_bf16(am, bfr, acc[m], 0, 0, 0);
        }
    }
    __syncthreads();            // S reads done -> reuse LDS for reduction
    double (*redd)[2 * OC] = (double(*)[2 * OC])Sl;

    int C = tile * 64 + colg;   // global col = n*8+b
    float yv[4 * MW];
#pragma unroll
    for (int m = 0; m < MW; m++)
#pragma unroll
        for (int i = 0; i < 4; i++) {
            int o = m * 16 + q * 4 + i;
            float y = acc[m][i] + bias[o];
            yv[m * 4 + i] = y;
            Yb[(size_t)C * OC + o] = f2bf(y);
        }
    // per-register butterfly keeps only 2 doubles live
#pragma unroll
    for (int r = 0; r < 4 * MW; r++) {
        double ps = (double)yv[r];
        double pq = (double)yv[r] * (double)yv[r];
#pragma unroll
        for (int d = 1; d < 16; d <<= 1) {
            ps += __shfl_xor(ps, d);
            pq += __shfl_xor(pq, d);
        }
        if (cl == 0) {
            int o = (r >> 2) * 16 + q * 4 + (r & 3);
            redd[wv][o] = ps;
            redd[wv][OC + o] = pq;
        }
    }
    __syncthreads();
    if (tid < 2 * OC) {
        double v = redd[0][tid] + redd[1][tid] + redd[2][tid] + redd[3][tid];
        Part[(size_t)tile * (2 * OC) + tid] = v;   // contention-free store
    }
}

// ---------------- BN reduce+finalize: one block per channel ----------------
__global__ __launch_bounds__(256, 8)
void bn_reduce(const double* __restrict__ Part,
               const float* __restrict__ g, const float* __restrict__ be,
               float* __restrict__ sc, float* __restrict__ sh, int OC) {
    int o = blockIdx.x;
    int tid = threadIdx.x;
    double s = 0.0, q = 0.0;
    for (int t = tid; t < NT_TILES; t += 256) {
        const double* p = Part + (size_t)t * (2 * OC);
        s += p[o];
        q += p[OC + o];
    }
#pragma unroll
    for (int d = 1; d < 64; d <<= 1) {
        s += __shfl_xor(s, d);
        q += __shfl_xor(q, d);
    }
    __shared__ double red[8];
    int wv = tid >> 6;
    if ((tid & 63) == 0) { red[wv] = s; red[4 + wv] = q; }
    __syncthreads();
    if (tid == 0) {
        double S = red[0] + red[1] + red[2] + red[3];
        double Q = red[4] + red[5] + red[6] + red[7];
        double cnt = (double)N2C * 8.0;
        double mean = S / cnt;
        double var = Q / cnt - mean * mean;
        double rs = 1.0 / sqrt(var + 1e-5);
        double scale = (double)g[o] * rs;
        sc[o] = (float)scale;
        sh[o] = (float)((double)be[o] - mean * scale);
    }
}

// ---------------- pool: 16 m per block; lane writes a full 64B line ----------------
__global__ __launch_bounds__(512, 4)
void pool_kernel(const unsigned short* __restrict__ Y3, const int* __restrict__ pidx,
                 const float* __restrict__ sc, const float* __restrict__ sh,
                 float* __restrict__ out) {
    int m0 = blockIdx.x * 16;
    int tid = threadIdx.x;      // b*64 + o
    int o = tid & 63;
    float s = sc[o], h = sh[o];
    float mx[16];
    int jn[9];
#pragma unroll
    for (int k = 0; k < 9; k++) jn[k] = pidx[m0 * 9 + k];
#pragma unroll 1
    for (int mi = 0; mi < 16; mi++) {
        int jc[9];
#pragma unroll
        for (int k = 0; k < 9; k++) jc[k] = jn[k];
        if (mi < 15) {
#pragma unroll
            for (int k = 0; k < 9; k++) jn[k] = pidx[(m0 + mi + 1) * 9 + k];
        }
        float v0 = 0.f;
#pragma unroll
        for (int k = 0; k < 9; k++) {
            float v = bf2f(Y3[(size_t)jc[k] * 512 + tid]);
            v0 = fmaxf(v0, fmaf(v, s, h));
        }
        mx[mi] = fmaxf(v0, 0.f);
    }
    float* op = out + (size_t)tid * 3136 + m0;
#pragma unroll
    for (int mi = 0; mi < 16; mi++) op[mi] = mx[mi];
}

extern "C" void kernel_launch(void* const* d_in, const int* in_sizes, int n_in,
                              void* d_out, int out_size, void* d_ws, size_t ws_size,
                              hipStream_t stream) {
    const float* x    = (const float*)d_in[0];
    const int*   nbr1 = (const int*)d_in[1];
    const float* off1 = (const float*)d_in[2];
    const int*   nbr2 = (const int*)d_in[3];
    const float* off2 = (const float*)d_in[4];
    const int*   pidx = (const int*)d_in[5];
    const float* Wh   = (const float*)d_in[6];
    const float* bh   = (const float*)d_in[7];
    const float* Wo   = (const float*)d_in[8];
    const float* bo   = (const float*)d_in[9];
    const float* W1   = (const float*)d_in[10];
    const float* b1   = (const float*)d_in[11];
    const float* W2   = (const float*)d_in[12];
    const float* b2   = (const float*)d_in[13];
    const float* W3   = (const float*)d_in[14];
    const float* b3   = (const float*)d_in[15];
    const float* g1   = (const float*)d_in[16];
    const float* be1  = (const float*)d_in[17];
    const float* g2   = (const float*)d_in[18];
    const float* be2  = (const float*)d_in[19];
    const float* g3   = (const float*)d_in[20];
    const float* be3  = (const float*)d_in[21];

    char* ws = (char*)d_ws;
    size_t off = 0;
    auto alloc = [&](size_t bytes) -> void* {
        void* p = ws + off;
        off += (bytes + 255) & ~(size_t)255;
        return p;
    };
    // Big shared S buffer (57.8 MB): used as S2/S3 operand for layers 2&3.
    // S1 (6.4MB), X0b (2.4MB), A1 (4.1MB) alias its head — all dead before
    // the first s32_kernel writes S in full.
    unsigned short* S   = (unsigned short*)alloc((size_t)N2C * 8 * 288 * 2);
    unsigned short* S1  = S;                                           // [0, 6.42MB)
    unsigned short* X0b = (unsigned short*)((char*)S + (8u << 20));    // 2.41MB
    float*          A1  = (float*)((char*)S + (12u << 20));            // 4.07MB
    float*          A2  = (float*)alloc((size_t)N2C * 81 * 4);
    // Y buffers: Y3b (12.8MB) aliases [Y1b | Y2b] (each dead before Y3 write)
    unsigned short* Ybuf = (unsigned short*)alloc((size_t)N2C * 8 * 64 * 2);
    unsigned short* Y1b = Ybuf;
    unsigned short* Y2b = Ybuf + (size_t)N2C * 8 * 32;
    unsigned short* Y3b = Ybuf;
    unsigned short* W1p = (unsigned short*)alloc(32 * 32 * 2);
    unsigned short* W2p = (unsigned short*)alloc(32 * 288 * 2);
    unsigned short* W3p = (unsigned short*)alloc(64 * 288 * 2);
    double* Part  = (double*)alloc((size_t)NT_TILES * 128 * 8);        // 1.6MB
    float*  scbuf = (float*)alloc(256 * 4);

    float* sc1 = scbuf;       float* sh1 = scbuf + 32;
    float* sc2 = scbuf + 64;  float* sh2 = scbuf + 96;
    float* sc3 = scbuf + 128; float* sh3 = scbuf + 192;

    hipMemsetAsync(S1, 0, (size_t)N2C * 8 * 32 * 2, stream);   // zero K-pad slots

    transpose_x<<<N1C / 64, 256, 0, stream>>>(x, X0b);
    mlp_kernel<<<(N2C * 9 + 255) / 256, 256, 0, stream>>>(off1, Wh, bh, Wo, bo, A1, N2C * 9);
    mlp_kernel<<<(N2C * 9 + 255) / 256, 256, 0, stream>>>(off2, Wh, bh, Wo, bo, A2, N2C * 9);
    pad_w<<<(32 * 32 + 255) / 256, 256, 0, stream>>>(W1, W1p, 32, 3, 1, 32 * 32);
    pad_w<<<(32 * 288 + 255) / 256, 256, 0, stream>>>(W2, W2p, 32, 32, 9, 32 * 288);
    pad_w<<<(64 * 288 + 255) / 256, 256, 0, stream>>>(W3, W3p, 64, 32, 9, 64 * 288);

    // ---- layer 1 ----
    s1_kernel<<<N2C * 24 / 256, 256, 0, stream>>>(X0b, nbr1, A1, S1);
    gemm_kernel<32, 2><<<NT_TILES, 256, 0, stream>>>(S1, W1p, b1, Y1b, Part);
    bn_reduce<<<32, 256, 0, stream>>>(Part, g1, be1, sc1, sh1, 32);

    // ---- layer 2 ----
    s32_kernel<<<N2C, 256, 0, stream>>>(Y1b, nbr2, A2, sc1, sh1, S);
    gemm_kernel<288, 2><<<NT_TILES, 256, 0, stream>>>(S, W2p, b2, Y2b, Part);
    bn_reduce<<<32, 256, 0, stream>>>(Part, g2, be2, sc2, sh2, 32);

    // ---- layer 3 (single gather pass even though OC=64) ----
    s32_kernel<<<N2C, 256, 0, stream>>>(Y2b, nbr2, A2, sc2, sh2, S);
    gemm_kernel<288, 4><<<NT_TILES, 256, 0, stream>>>(S, W3p, b3, Y3b, Part);
    bn_reduce<<<64, 256, 0, stream>>>(Part, g3, be3, sc3, sh3, 64);

    pool_kernel<<<N3C / 16, 512, 0, stream>>>(Y3b, pidx, sc3, sh3, (float*)d_out);
}

// Round 5
// 254.578 us; speedup vs baseline: 2.2377x; 1.0566x over previous
//
#include <hip/hip_runtime.h>
#include <math.h>

#define N1C 50176
#define N2C 12544
#define N3C 3136
#define NT_TILES (N2C * 8 / 64)   // 1568 conv tiles (64 cols each)

typedef __attribute__((ext_vector_type(8))) short bf16x8;
typedef __attribute__((ext_vector_type(4))) float f32x4;

__device__ __forceinline__ unsigned short f2bf(float f) {
    unsigned u = __builtin_bit_cast(unsigned, f);
    u += 0x7fffu + ((u >> 16) & 1u);
    return (unsigned short)(u >> 16);
}
__device__ __forceinline__ float bf2f(unsigned short u) {
    return __builtin_bit_cast(float, (unsigned)u << 16);
}

// ---------------- fused prologue: transpose | mlp(off1+off2) | pad_w(W1,W2,W3) ----------------
// block ranges: [0,784) transpose, [784,1666) mlp, [1666,1778) pad_w
#define TRB (N1C / 64)            // 784
#define MLB (2 * N2C * 9 / 256)   // 882
#define PWB 112                   // (1024+9216+18432)/256

__device__ __forceinline__ void pad_one(int i, const float* __restrict__ W,
                                        unsigned short* __restrict__ Wp,
                                        int OC, int CIN, int KT) {
    int j = i & 7;
    int op = (i >> 3) & 31;
    int q = (i >> 8) & 3;
    int kt = (i >> 10) % KT;
    int g = i / (KT * 1024);
    int kp = kt * 32 + q * 8 + j;
    int t = kp / CIN, c = kp - t * CIN;
    int o = g * 32 + op;
    float v = (t < 9 && o < OC) ? W[(o * CIN + c) * 9 + t] : 0.f;
    Wp[i] = f2bf(v);
}

__global__ void prologue_kernel(const float* __restrict__ x, unsigned short* __restrict__ X0,
                                const float* __restrict__ off1, const float* __restrict__ off2,
                                const float* __restrict__ Wh, const float* __restrict__ bh,
                                const float* __restrict__ Wo, const float* __restrict__ bo,
                                float* __restrict__ A1, float* __restrict__ A2,
                                const float* __restrict__ W1, const float* __restrict__ W2,
                                const float* __restrict__ W3,
                                unsigned short* __restrict__ W1p, unsigned short* __restrict__ W2p,
                                unsigned short* __restrict__ W3p) {
    __shared__ float T[64][25];
    int blk = blockIdx.x;
    int tid = threadIdx.x;
    if (blk < TRB) {
        // transpose x (B,3,N1) -> X0 bf16 [n][b*3+c]
        int n0 = blk * 64;
        for (int r = tid; r < 24 * 64; r += 256) {
            int cb = r >> 6;
            int nn = r & 63;
            T[nn][cb] = x[cb * N1C + n0 + nn];
        }
        __syncthreads();
        for (int w = tid; w < 64 * 24; w += 256) {
            int nn = w / 24;
            int u = w - nn * 24;
            X0[(n0 + nn) * 24 + u] = f2bf(T[nn][u]);
        }
    } else if (blk < TRB + MLB) {
        int idx = (blk - TRB) * 256 + tid;       // < 2*N2C*9 exactly
        const float* offp;
        float* Ap;
        if (idx < N2C * 9) { offp = off1 + idx * 2; Ap = A1 + idx * 9; }
        else { int i2 = idx - N2C * 9; offp = off2 + i2 * 2; Ap = A2 + i2 * 9; }
        float o0 = offp[0], o1 = offp[1];
        float out[9];
#pragma unroll
        for (int t = 0; t < 9; t++) out[t] = bo[t];
#pragma unroll
        for (int h = 0; h < 32; h++) {
            float hv = fmaxf(o0 * Wh[h] + o1 * Wh[32 + h] + bh[h], 0.f);
#pragma unroll
            for (int t = 0; t < 9; t++) out[t] += hv * Wo[h * 9 + t];
        }
#pragma unroll
        for (int t = 0; t < 9; t++) Ap[t] = out[t];
    } else {
        int i = (blk - TRB - MLB) * 256 + tid;   // < 28672 exactly
        if (i < 1024) pad_one(i, W1, W1p, 32, 3, 1);
        else if (i < 10240) pad_one(i - 1024, W2, W2p, 32, 32, 9);
        else pad_one(i - 10240, W3, W3p, 64, 32, 9);
    }
}

// ---------------- fused interp-conv: gather+weight -> LDS S -> MFMA ----------------
// Xin bf16: CIN=3: [n][b*3+c]; CIN=32: [col][c] (col=n*8+b)
// Yb bf16:  [col][OC];  Part[tile][2*OC] BN partials (double)
template <int CIN, int MW, bool HAS_BN>   // MW = OC/16
__global__ __launch_bounds__(256, 4)
void conv_kernel(const unsigned short* __restrict__ Xin,
                 const int* __restrict__ nbr,
                 const float* __restrict__ A,
                 const unsigned short* __restrict__ Wp,   // fragment-major bf16
                 const float* __restrict__ bias,
                 const float* __restrict__ bnsc,
                 const float* __restrict__ bnsh,
                 unsigned short* __restrict__ Yb,
                 double* __restrict__ Part) {
    constexpr int OC = MW * 16;
    constexpr int KREAL = 9 * CIN;
    constexpr int KROW = (KREAL + 31) & ~31;  // 32 / 288
    constexpr int KT = KROW / 32;
    constexpr int KSTR = KROW + 8;
    __shared__ alignas(16) short S[64 * KSTR];

    int tid = threadIdx.x;
    int tile = blockIdx.x;
    int n0 = tile * 8;

    if constexpr (KROW != KREAL) {            // CIN=3: zero pad slots
        for (int i = tid; i < 64 * KSTR; i += 256) S[i] = 0;
        __syncthreads();
    }

    // ---- phase A: S[col][t*CIN+c] = sum_k a[n,k,t] * bnrelu(feat) ----
    if constexpr (CIN == 3) {
        if (tid < 192) {
            int nsub = tid / 24;
            int u = tid - nsub * 24;          // u = b*3+c
            int b = u / 3, c = u - b * 3;
            int n = n0 + nsub;
            const int* nb = nbr + n * 9;
            const float* Ar = A + n * 81;
            float s[9];
#pragma unroll
            for (int t = 0; t < 9; t++) s[t] = 0.f;
#pragma unroll
            for (int k = 0; k < 9; k++) {
                float f = bf2f(Xin[nb[k] * 24 + u]);
#pragma unroll
                for (int t = 0; t < 9; t++) s[t] = fmaf(Ar[k * 9 + t], f, s[t]);
            }
            int col = nsub * 8 + b;
#pragma unroll
            for (int t = 0; t < 9; t++) S[col * KSTR + t * 3 + c] = (short)f2bf(s[t]);
        }
    } else {
        int c = tid & 31, b = tid >> 5;
        float sc = 1.f, sh = 0.f;
        if (HAS_BN) { sc = bnsc[c]; sh = bnsh[c]; }
        const int* nb = nbr + n0 * 9;
        float f[9];
#pragma unroll
        for (int k = 0; k < 9; k++) f[k] = bf2f(Xin[(size_t)nb[k] * 256 + tid]);
#pragma unroll 1
        for (int nsub = 0; nsub < 8; nsub++) {
            float fn[9];
            int nn = (nsub < 7) ? nsub + 1 : 7;
#pragma unroll
            for (int k = 0; k < 9; k++) fn[k] = bf2f(Xin[(size_t)nb[nn * 9 + k] * 256 + tid]);
            const float* Ar = A + (n0 + nsub) * 81;
            float s[9];
#pragma unroll
            for (int t = 0; t < 9; t++) s[t] = 0.f;
#pragma unroll
            for (int k = 0; k < 9; k++) {
                float v = f[k];
                if (HAS_BN) v = fmaxf(fmaf(v, sc, sh), 0.f);
#pragma unroll
                for (int t = 0; t < 9; t++) s[t] = fmaf(Ar[k * 9 + t], v, s[t]);
            }
            int col = nsub * 8 + b;
#pragma unroll
            for (int t = 0; t < 9; t++) S[col * KSTR + t * 32 + c] = (short)f2bf(s[t]);
#pragma unroll
            for (int k = 0; k < 9; k++) f[k] = fn[k];
        }
    }
    __syncthreads();

    // ---- phase B: MFMA, W frags straight from global (L2-hot) ----
    int lane = tid & 63, wv = tid >> 6, q = lane >> 4, cl = lane & 15;
    int colg = wv * 16 + cl;

    const bf16x8* wf = (const bf16x8*)Wp;
    f32x4 acc[MW];
#pragma unroll
    for (int m = 0; m < MW; m++) acc[m] = (f32x4){0.f, 0.f, 0.f, 0.f};
#pragma unroll
    for (int kt = 0; kt < KT; kt++) {
        bf16x8 bfr = *(const bf16x8*)&S[colg * KSTR + kt * 32 + q * 8];
#pragma unroll
        for (int m = 0; m < MW; m++) {
            const bf16x8* wg = wf + (m >> 1) * (KT * 128);
            bf16x8 am = wg[(kt * 4 + q) * 32 + cl + (m & 1) * 16];
            acc[m] = __builtin_amdgcn_mfma_f32_16x16x32_bf16(am, bfr, acc[m], 0, 0, 0);
        }
    }
    __syncthreads();            // S reads done -> reuse LDS for reduction
    double (*redd)[2 * OC] = (double(*)[2 * OC])S;

    int C = tile * 64 + colg;   // global col = n*8+b
    float yv[4 * MW];
#pragma unroll
    for (int m = 0; m < MW; m++)
#pragma unroll
        for (int i = 0; i < 4; i++) {
            int o = m * 16 + q * 4 + i;
            float y = acc[m][i] + bias[o];
            yv[m * 4 + i] = y;
            Yb[(size_t)C * OC + o] = f2bf(y);
        }
#pragma unroll
    for (int r = 0; r < 4 * MW; r++) {
        double ps = (double)yv[r];
        double pq = (double)yv[r] * (double)yv[r];
#pragma unroll
        for (int d = 1; d < 16; d <<= 1) {
            ps += __shfl_xor(ps, d);
            pq += __shfl_xor(pq, d);
        }
        if (cl == 0) {
            int o = (r >> 2) * 16 + q * 4 + (r & 3);
            redd[wv][o] = ps;
            redd[wv][OC + o] = pq;
        }
    }
    __syncthreads();
    if (tid < 2 * OC) {
        double v = redd[0][tid] + redd[1][tid] + redd[2][tid] + redd[3][tid];
        Part[(size_t)tile * (2 * OC) + tid] = v;   // contention-free store
    }
}

// ---------------- BN reduce+finalize: one block per channel ----------------
__global__ __launch_bounds__(256, 8)
void bn_reduce(const double* __restrict__ Part,
               const float* __restrict__ g, const float* __restrict__ be,
               float* __restrict__ sc, float* __restrict__ sh, int OC) {
    int o = blockIdx.x;
    int tid = threadIdx.x;
    double s = 0.0, q = 0.0;
    for (int t = tid; t < NT_TILES; t += 256) {
        const double* p = Part + (size_t)t * (2 * OC);
        s += p[o];
        q += p[OC + o];
    }
#pragma unroll
    for (int d = 1; d < 64; d <<= 1) {
        s += __shfl_xor(s, d);
        q += __shfl_xor(q, d);
    }
    __shared__ double red[8];
    int wv = tid >> 6;
    if ((tid & 63) == 0) { red[wv] = s; red[4 + wv] = q; }
    __syncthreads();
    if (tid == 0) {
        double S = red[0] + red[1] + red[2] + red[3];
        double Q = red[4] + red[5] + red[6] + red[7];
        double cnt = (double)N2C * 8.0;
        double mean = S / cnt;
        double var = Q / cnt - mean * mean;
        double rs = 1.0 / sqrt(var + 1e-5);
        double scale = (double)g[o] * rs;
        sc[o] = (float)scale;
        sh[o] = (float)((double)be[o] - mean * scale);
    }
}

// ---------------- pool: 16 m per block; lane writes a full 64B line ----------------
__global__ __launch_bounds__(512, 4)
void pool_kernel(const unsigned short* __restrict__ Y3, const int* __restrict__ pidx,
                 const float* __restrict__ sc, const float* __restrict__ sh,
                 float* __restrict__ out) {
    int m0 = blockIdx.x * 16;
    int tid = threadIdx.x;      // b*64 + o
    int o = tid & 63;
    float s = sc[o], h = sh[o];
    float mx[16];
    int jn[9];
#pragma unroll
    for (int k = 0; k < 9; k++) jn[k] = pidx[m0 * 9 + k];
#pragma unroll 1
    for (int mi = 0; mi < 16; mi++) {
        int jc[9];
#pragma unroll
        for (int k = 0; k < 9; k++) jc[k] = jn[k];
        if (mi < 15) {
#pragma unroll
            for (int k = 0; k < 9; k++) jn[k] = pidx[(m0 + mi + 1) * 9 + k];
        }
        float v0 = 0.f;
#pragma unroll
        for (int k = 0; k < 9; k++) {
            float v = bf2f(Y3[(size_t)jc[k] * 512 + tid]);
            v0 = fmaxf(v0, fmaf(v, s, h));
        }
        mx[mi] = fmaxf(v0, 0.f);
    }
    float* op = out + (size_t)tid * 3136 + m0;
#pragma unroll
    for (int mi = 0; mi < 16; mi++) op[mi] = mx[mi];
}

extern "C" void kernel_launch(void* const* d_in, const int* in_sizes, int n_in,
                              void* d_out, int out_size, void* d_ws, size_t ws_size,
                              hipStream_t stream) {
    const float* x    = (const float*)d_in[0];
    const int*   nbr1 = (const int*)d_in[1];
    const float* off1 = (const float*)d_in[2];
    const int*   nbr2 = (const int*)d_in[3];
    const float* off2 = (const float*)d_in[4];
    const int*   pidx = (const int*)d_in[5];
    const float* Wh   = (const float*)d_in[6];
    const float* bh   = (const float*)d_in[7];
    const float* Wo   = (const float*)d_in[8];
    const float* bo   = (const float*)d_in[9];
    const float* W1   = (const float*)d_in[10];
    const float* b1   = (const float*)d_in[11];
    const float* W2   = (const float*)d_in[12];
    const float* b2   = (const float*)d_in[13];
    const float* W3   = (const float*)d_in[14];
    const float* b3   = (const float*)d_in[15];
    const float* g1   = (const float*)d_in[16];
    const float* be1  = (const float*)d_in[17];
    const float* g2   = (const float*)d_in[18];
    const float* be2  = (const float*)d_in[19];
    const float* g3   = (const float*)d_in[20];
    const float* be3  = (const float*)d_in[21];

    char* ws = (char*)d_ws;
    size_t off = 0;
    auto alloc = [&](size_t bytes) -> void* {
        void* p = ws + off;
        off += (bytes + 255) & ~(size_t)255;
        return p;
    };
    unsigned short* X0b = (unsigned short*)alloc((size_t)N1C * 24 * 2);   // 2.4MB
    float* A1 = (float*)alloc((size_t)N2C * 81 * 4);                      // 4.1MB
    float* A2 = (float*)alloc((size_t)N2C * 81 * 4);                      // 4.1MB
    unsigned short* Y1b = (unsigned short*)alloc((size_t)N2C * 8 * 32 * 2);  // 6.4MB
    unsigned short* Y2b = (unsigned short*)alloc((size_t)N2C * 8 * 32 * 2);  // 6.4MB
    unsigned short* Y3b = (unsigned short*)alloc((size_t)N2C * 8 * 64 * 2);  // 12.8MB
    unsigned short* W1p = (unsigned short*)alloc(32 * 32 * 2);
    unsigned short* W2p = (unsigned short*)alloc(32 * 288 * 2);
    unsigned short* W3p = (unsigned short*)alloc(64 * 288 * 2);
    double* Part  = (double*)alloc((size_t)NT_TILES * 128 * 8);           // 1.6MB
    float*  scbuf = (float*)alloc(256 * 4);

    float* sc1 = scbuf;       float* sh1 = scbuf + 32;
    float* sc2 = scbuf + 64;  float* sh2 = scbuf + 96;
    float* sc3 = scbuf + 128; float* sh3 = scbuf + 192;

    prologue_kernel<<<TRB + MLB + PWB, 256, 0, stream>>>(
        x, X0b, off1, off2, Wh, bh, Wo, bo, A1, A2, W1, W2, W3, W1p, W2p, W3p);

    conv_kernel<3, 2, false><<<NT_TILES, 256, 0, stream>>>(
        X0b, nbr1, A1, W1p, b1, nullptr, nullptr, Y1b, Part);
    bn_reduce<<<32, 256, 0, stream>>>(Part, g1, be1, sc1, sh1, 32);

    conv_kernel<32, 2, true><<<NT_TILES, 256, 0, stream>>>(
        Y1b, nbr2, A2, W2p, b2, sc1, sh1, Y2b, Part);
    bn_reduce<<<32, 256, 0, stream>>>(Part, g2, be2, sc2, sh2, 32);

    conv_kernel<32, 4, true><<<NT_TILES, 256, 0, stream>>>(
        Y2b, nbr2, A2, W3p, b3, sc2, sh2, Y3b, Part);
    bn_reduce<<<64, 256, 0, stream>>>(Part, g3, be3, sc3, sh3, 64);

    pool_kernel<<<N3C / 16, 512, 0, stream>>>(Y3b, pidx, sc3, sh3, (float*)d_out);
}

// Round 6
// 217.268 us; speedup vs baseline: 2.6220x; 1.1717x over previous
//
#include <hip/hip_runtime.h>
#include <math.h>

#define N1C 50176
#define N2C 12544
#define N3C 3136
#define NT_TILES (N2C * 8 / 64)   // 1568 conv tiles (64 cols each)

typedef __attribute__((ext_vector_type(8))) short bf16x8;
typedef __attribute__((ext_vector_type(4))) float f32x4;

__device__ __forceinline__ unsigned short f2bf(float f) {
    unsigned u = __builtin_bit_cast(unsigned, f);
    u += 0x7fffu + ((u >> 16) & 1u);
    return (unsigned short)(u >> 16);
}
__device__ __forceinline__ unsigned packbf(float a, float b) {
    return (unsigned)f2bf(a) | ((unsigned)f2bf(b) << 16);
}
__device__ __forceinline__ float bf2f(unsigned short u) {
    return __builtin_bit_cast(float, (unsigned)u << 16);
}
__device__ __forceinline__ float bflo(unsigned u) {
    return __builtin_bit_cast(float, u << 16);
}
__device__ __forceinline__ float bfhi(unsigned u) {
    return __builtin_bit_cast(float, u & 0xffff0000u);
}

// ---------------- fused prologue: transpose | mlp(off1+off2) | pad_w(W1,W2,W3) ----------------
#define TRB (N1C / 64)            // 784
#define MLB (2 * N2C * 9 / 256)   // 882
#define PWB 112                   // (1024+9216+18432)/256

__device__ __forceinline__ void pad_one(int i, const float* __restrict__ W,
                                        unsigned short* __restrict__ Wp,
                                        int OC, int CIN, int KT) {
    int j = i & 7;
    int op = (i >> 3) & 31;
    int q = (i >> 8) & 3;
    int kt = (i >> 10) % KT;
    int g = i / (KT * 1024);
    int kp = kt * 32 + q * 8 + j;
    int t = kp / CIN, c = kp - t * CIN;
    int o = g * 32 + op;
    float v = (t < 9 && o < OC) ? W[(o * CIN + c) * 9 + t] : 0.f;
    Wp[i] = f2bf(v);
}

__global__ void prologue_kernel(const float* __restrict__ x, unsigned short* __restrict__ X0,
                                const float* __restrict__ off1, const float* __restrict__ off2,
                                const float* __restrict__ Wh, const float* __restrict__ bh,
                                const float* __restrict__ Wo, const float* __restrict__ bo,
                                float* __restrict__ A1, float* __restrict__ A2,
                                const float* __restrict__ W1, const float* __restrict__ W2,
                                const float* __restrict__ W3,
                                unsigned short* __restrict__ W1p, unsigned short* __restrict__ W2p,
                                unsigned short* __restrict__ W3p) {
    __shared__ float T[64][25];
    int blk = blockIdx.x;
    int tid = threadIdx.x;
    if (blk < TRB) {
        int n0 = blk * 64;
        for (int r = tid; r < 24 * 64; r += 256) {
            int cb = r >> 6;
            int nn = r & 63;
            T[nn][cb] = x[cb * N1C + n0 + nn];
        }
        __syncthreads();
        for (int w = tid; w < 64 * 24; w += 256) {
            int nn = w / 24;
            int u = w - nn * 24;
            X0[(n0 + nn) * 24 + u] = f2bf(T[nn][u]);
        }
    } else if (blk < TRB + MLB) {
        int idx = (blk - TRB) * 256 + tid;
        const float* offp;
        float* Ap;
        if (idx < N2C * 9) { offp = off1 + idx * 2; Ap = A1 + idx * 9; }
        else { int i2 = idx - N2C * 9; offp = off2 + i2 * 2; Ap = A2 + i2 * 9; }
        float o0 = offp[0], o1 = offp[1];
        float out[9];
#pragma unroll
        for (int t = 0; t < 9; t++) out[t] = bo[t];
#pragma unroll
        for (int h = 0; h < 32; h++) {
            float hv = fmaxf(o0 * Wh[h] + o1 * Wh[32 + h] + bh[h], 0.f);
#pragma unroll
            for (int t = 0; t < 9; t++) out[t] += hv * Wo[h * 9 + t];
        }
#pragma unroll
        for (int t = 0; t < 9; t++) Ap[t] = out[t];
    } else {
        int i = (blk - TRB - MLB) * 256 + tid;
        if (i < 1024) pad_one(i, W1, W1p, 32, 3, 1);
        else if (i < 10240) pad_one(i - 1024, W2, W2p, 32, 32, 9);
        else pad_one(i - 10240, W3, W3p, 64, 32, 9);
    }
}

// ---------------- fused interp-conv: gather+weight -> LDS S -> MFMA ----------------
// Xin bf16: CIN=3: [n][b*3+c]; CIN=32: [col][c] (col=n*8+b)
// Yb bf16:  [col][OC];  Part[2*OC][NT_TILES] BN partials (double, transposed)
template <int CIN, int MW, bool HAS_BN>   // MW = OC/16
__global__ __launch_bounds__(256, 4)
void conv_kernel(const unsigned short* __restrict__ Xin,
                 const int* __restrict__ nbr,
                 const float* __restrict__ A,
                 const unsigned short* __restrict__ Wp,   // fragment-major bf16
                 const float* __restrict__ bias,
                 const float* __restrict__ bnsc,
                 const float* __restrict__ bnsh,
                 unsigned short* __restrict__ Yb,
                 double* __restrict__ Part) {
    constexpr int OC = MW * 16;
    constexpr int KREAL = 9 * CIN;
    constexpr int KROW = (KREAL + 31) & ~31;  // 32 / 288
    constexpr int KT = KROW / 32;
    constexpr int KSTR = KROW + 8;            // 40 / 296 (even -> uint-safe)
    __shared__ alignas(16) short S[64 * KSTR];

    int tid = threadIdx.x;
    int tile = blockIdx.x;
    int n0 = tile * 8;

    if constexpr (KROW != KREAL) {            // CIN=3: zero pad slots
        for (int i = tid; i < 64 * KSTR; i += 256) S[i] = 0;
        __syncthreads();
    }

    // ---- phase A: S[col][t*CIN+c] = sum_k a[n,k,t] * bnrelu(feat) ----
    if constexpr (CIN == 3) {
        if (tid < 192) {
            int nsub = tid / 24;
            int u = tid - nsub * 24;          // u = b*3+c
            int b = u / 3, c = u - b * 3;
            int n = n0 + nsub;
            const int* nb = nbr + n * 9;
            const float* Ar = A + n * 81;
            float s[9];
#pragma unroll
            for (int t = 0; t < 9; t++) s[t] = 0.f;
#pragma unroll
            for (int k = 0; k < 9; k++) {
                float f = bf2f(Xin[nb[k] * 24 + u]);
#pragma unroll
                for (int t = 0; t < 9; t++) s[t] = fmaf(Ar[k * 9 + t], f, s[t]);
            }
            int col = nsub * 8 + b;
#pragma unroll
            for (int t = 0; t < 9; t++) S[col * KSTR + t * 3 + c] = (short)f2bf(s[t]);
        }
    } else {
        // thread = (nhalf, b, c2): nhalf picks nodes 0-3 / 4-7, uint = 2 channels
        int nhalf = __builtin_amdgcn_readfirstlane(tid >> 7);   // wave-uniform
        int rem = tid & 127;
        int b = rem >> 4, c2 = rem & 15;
        float sc0 = 1.f, sh0 = 0.f, sc1 = 1.f, sh1 = 0.f;
        if (HAS_BN) {
            sc0 = bnsc[2 * c2];     sc1 = bnsc[2 * c2 + 1];
            sh0 = bnsh[2 * c2];     sh1 = bnsh[2 * c2 + 1];
        }
        const unsigned* Xu = (const unsigned*)Xin;
        int nbase = n0 + nhalf * 4;
        unsigned fu[36];                       // all 36 gathers in flight upfront
#pragma unroll
        for (int g = 0; g < 4; g++)
#pragma unroll
            for (int k = 0; k < 9; k++) {
                int j = nbr[(nbase + g) * 9 + k];      // scalar (wave-uniform)
                fu[g * 9 + k] = Xu[(size_t)j * 128 + rem];
            }
#pragma unroll
        for (int g = 0; g < 4; g++) {
            const float* Ar = A + (nbase + g) * 81;
            float s0[9], s1[9];
#pragma unroll
            for (int t = 0; t < 9; t++) { s0[t] = 0.f; s1[t] = 0.f; }
#pragma unroll
            for (int k = 0; k < 9; k++) {
                unsigned u = fu[g * 9 + k];
                float lo = bflo(u), hi = bfhi(u);
                if (HAS_BN) {
                    lo = fmaxf(fmaf(lo, sc0, sh0), 0.f);
                    hi = fmaxf(fmaf(hi, sc1, sh1), 0.f);
                }
#pragma unroll
                for (int t = 0; t < 9; t++) {
                    float a = Ar[k * 9 + t];
                    s0[t] = fmaf(a, lo, s0[t]);
                    s1[t] = fmaf(a, hi, s1[t]);
                }
            }
            int col = (nhalf * 4 + g) * 8 + b;
            unsigned* Srow = (unsigned*)&S[col * KSTR];
#pragma unroll
            for (int t = 0; t < 9; t++) Srow[t * 16 + c2] = packbf(s0[t], s1[t]);
        }
    }
    __syncthreads();

    // ---- phase B: MFMA, W frags straight from global (L2-hot) ----
    int lane = tid & 63, wv = tid >> 6, q = lane >> 4, cl = lane & 15;
    int colg = wv * 16 + cl;

    const bf16x8* wf = (const bf16x8*)Wp;
    f32x4 acc[MW];
#pragma unroll
    for (int m = 0; m < MW; m++) acc[m] = (f32x4){0.f, 0.f, 0.f, 0.f};
#pragma unroll
    for (int kt = 0; kt < KT; kt++) {
        bf16x8 bfr = *(const bf16x8*)&S[colg * KSTR + kt * 32 + q * 8];
#pragma unroll
        for (int m = 0; m < MW; m++) {
            const bf16x8* wg = wf + (m >> 1) * (KT * 128);
            bf16x8 am = wg[(kt * 4 + q) * 32 + cl + (m & 1) * 16];
            acc[m] = __builtin_amdgcn_mfma_f32_16x16x32_bf16(am, bfr, acc[m], 0, 0, 0);
        }
    }
    __syncthreads();            // S reads done -> reuse LDS for reduction
    double (*redd)[2 * OC] = (double(*)[2 * OC])S;

    int C = tile * 64 + colg;   // global col = n*8+b
    float yv[4 * MW];
#pragma unroll
    for (int m = 0; m < MW; m++)
#pragma unroll
        for (int i = 0; i < 4; i++) {
            int o = m * 16 + q * 4 + i;
            float y = acc[m][i] + bias[o];
            yv[m * 4 + i] = y;
            Yb[(size_t)C * OC + o] = f2bf(y);
        }
#pragma unroll
    for (int r = 0; r < 4 * MW; r++) {
        double ps = (double)yv[r];
        double pq = (double)yv[r] * (double)yv[r];
#pragma unroll
        for (int d = 1; d < 16; d <<= 1) {
            ps += __shfl_xor(ps, d);
            pq += __shfl_xor(pq, d);
        }
        if (cl == 0) {
            int o = (r >> 2) * 16 + q * 4 + (r & 3);
            redd[wv][o] = ps;
            redd[wv][OC + o] = pq;
        }
    }
    __syncthreads();
    if (tid < 2 * OC) {
        double v = redd[0][tid] + redd[1][tid] + redd[2][tid] + redd[3][tid];
        Part[(size_t)tid * NT_TILES + tile] = v;   // transposed: coalesced in bn_reduce
    }
}

// ---------------- BN reduce+finalize: one block per channel ----------------
__global__ __launch_bounds__(256, 8)
void bn_reduce(const double* __restrict__ Part,
               const float* __restrict__ g, const float* __restrict__ be,
               float* __restrict__ sc, float* __restrict__ sh, int OC) {
    int o = blockIdx.x;
    int tid = threadIdx.x;
    const double* ps = Part + (size_t)o * NT_TILES;
    const double* pq = Part + (size_t)(OC + o) * NT_TILES;
    double s = 0.0, q = 0.0;
    for (int t = tid; t < NT_TILES; t += 256) {
        s += ps[t];
        q += pq[t];
    }
#pragma unroll
    for (int d = 1; d < 64; d <<= 1) {
        s += __shfl_xor(s, d);
        q += __shfl_xor(q, d);
    }
    __shared__ double red[8];
    int wv = tid >> 6;
    if ((tid & 63) == 0) { red[wv] = s; red[4 + wv] = q; }
    __syncthreads();
    if (tid == 0) {
        double S = red[0] + red[1] + red[2] + red[3];
        double Q = red[4] + red[5] + red[6] + red[7];
        double cnt = (double)N2C * 8.0;
        double mean = S / cnt;
        double var = Q / cnt - mean * mean;
        double rs = 1.0 / sqrt(var + 1e-5);
        double scale = (double)g[o] * rs;
        sc[o] = (float)scale;
        sh[o] = (float)((double)be[o] - mean * scale);
    }
}

// ---------------- pool: 8 m per block; lane writes a 32B run ----------------
__global__ __launch_bounds__(512, 4)
void pool_kernel(const unsigned short* __restrict__ Y3, const int* __restrict__ pidx,
                 const float* __restrict__ sc, const float* __restrict__ sh,
                 float* __restrict__ out) {
    int m0 = blockIdx.x * 8;
    int tid = threadIdx.x;      // b*64 + o
    int o = tid & 63;
    float s = sc[o], h = sh[o];
    float mx[8];
    int jn[9];
#pragma unroll
    for (int k = 0; k < 9; k++) jn[k] = pidx[m0 * 9 + k];
#pragma unroll 1
    for (int mi = 0; mi < 8; mi++) {
        int jc[9];
#pragma unroll
        for (int k = 0; k < 9; k++) jc[k] = jn[k];
        if (mi < 7) {
#pragma unroll
            for (int k = 0; k < 9; k++) jn[k] = pidx[(m0 + mi + 1) * 9 + k];
        }
        float v0 = 0.f;
#pragma unroll
        for (int k = 0; k < 9; k++) {
            float v = bf2f(Y3[(size_t)jc[k] * 512 + tid]);
            v0 = fmaxf(v0, fmaf(v, s, h));
        }
        mx[mi] = fmaxf(v0, 0.f);
    }
    float* op = out + (size_t)tid * 3136 + m0;
#pragma unroll
    for (int mi = 0; mi < 8; mi++) op[mi] = mx[mi];
}

extern "C" void kernel_launch(void* const* d_in, const int* in_sizes, int n_in,
                              void* d_out, int out_size, void* d_ws, size_t ws_size,
                              hipStream_t stream) {
    const float* x    = (const float*)d_in[0];
    const int*   nbr1 = (const int*)d_in[1];
    const float* off1 = (const float*)d_in[2];
    const int*   nbr2 = (const int*)d_in[3];
    const float* off2 = (const float*)d_in[4];
    const int*   pidx = (const int*)d_in[5];
    const float* Wh   = (const float*)d_in[6];
    const float* bh   = (const float*)d_in[7];
    const float* Wo   = (const float*)d_in[8];
    const float* bo   = (const float*)d_in[9];
    const float* W1   = (const float*)d_in[10];
    const float* b1   = (const float*)d_in[11];
    const float* W2   = (const float*)d_in[12];
    const float* b2   = (const float*)d_in[13];
    const float* W3   = (const float*)d_in[14];
    const float* b3   = (const float*)d_in[15];
    const float* g1   = (const float*)d_in[16];
    const float* be1  = (const float*)d_in[17];
    const float* g2   = (const float*)d_in[18];
    const float* be2  = (const float*)d_in[19];
    const float* g3   = (const float*)d_in[20];
    const float* be3  = (const float*)d_in[21];

    char* ws = (char*)d_ws;
    size_t off = 0;
    auto alloc = [&](size_t bytes) -> void* {
        void* p = ws + off;
        off += (bytes + 255) & ~(size_t)255;
        return p;
    };
    unsigned short* X0b = (unsigned short*)alloc((size_t)N1C * 24 * 2);   // 2.4MB
    float* A1 = (float*)alloc((size_t)N2C * 81 * 4);                      // 4.1MB
    float* A2 = (float*)alloc((size_t)N2C * 81 * 4);                      // 4.1MB
    unsigned short* Y1b = (unsigned short*)alloc((size_t)N2C * 8 * 32 * 2);  // 6.4MB
    unsigned short* Y2b = (unsigned short*)alloc((size_t)N2C * 8 * 32 * 2);  // 6.4MB
    unsigned short* Y3b = (unsigned short*)alloc((size_t)N2C * 8 * 64 * 2);  // 12.8MB
    unsigned short* W1p = (unsigned short*)alloc(32 * 32 * 2);
    unsigned short* W2p = (unsigned short*)alloc(32 * 288 * 2);
    unsigned short* W3p = (unsigned short*)alloc(64 * 288 * 2);
    double* Part  = (double*)alloc((size_t)NT_TILES * 128 * 8);           // 1.6MB
    float*  scbuf = (float*)alloc(256 * 4);

    float* sc1 = scbuf;       float* sh1 = scbuf + 32;
    float* sc2 = scbuf + 64;  float* sh2 = scbuf + 96;
    float* sc3 = scbuf + 128; float* sh3 = scbuf + 192;

    prologue_kernel<<<TRB + MLB + PWB, 256, 0, stream>>>(
        x, X0b, off1, off2, Wh, bh, Wo, bo, A1, A2, W1, W2, W3, W1p, W2p, W3p);

    conv_kernel<3, 2, false><<<NT_TILES, 256, 0, stream>>>(
        X0b, nbr1, A1, W1p, b1, nullptr, nullptr, Y1b, Part);
    bn_reduce<<<32, 256, 0, stream>>>(Part, g1, be1, sc1, sh1, 32);

    conv_kernel<32, 2, true><<<NT_TILES, 256, 0, stream>>>(
        Y1b, nbr2, A2, W2p, b2, sc1, sh1, Y2b, Part);
    bn_reduce<<<32, 256, 0, stream>>>(Part, g2, be2, sc2, sh2, 32);

    conv_kernel<32, 4, true><<<NT_TILES, 256, 0, stream>>>(
        Y2b, nbr2, A2, W3p, b3, sc2, sh2, Y3b, Part);
    bn_reduce<<<64, 256, 0, stream>>>(Part, g3, be3, sc3, sh3, 64);

    pool_kernel<<<N3C / 8, 512, 0, stream>>>(Y3b, pidx, sc3, sh3, (float*)d_out);
}